// Round 3
// baseline (432.349 us; speedup 1.0000x reference)
//
#include <hip/hip_runtime.h>
#include <stdint.h>

typedef __attribute__((ext_vector_type(4))) float floatx4;
typedef __attribute__((ext_vector_type(8))) short shortx8;

#define LN_EPS 1e-5f

__device__ __forceinline__ unsigned short f2b(float f) {
  unsigned u = __builtin_bit_cast(unsigned, f);
  u = (u + 0x7FFFu + ((u >> 16) & 1u)) >> 16;
  return (unsigned short)u;
}
__device__ __forceinline__ float b2f(unsigned short h) {
  return __builtin_bit_cast(float, (unsigned)h << 16);
}

// async global->LDS 16B: lds dest is wave-uniform base; lane i lands at base + i*16
__device__ __forceinline__ void g2l16(const unsigned short* g, unsigned short* l) {
  __builtin_amdgcn_global_load_lds(
      (const __attribute__((address_space(1))) unsigned int*)g,
      (__attribute__((address_space(3))) unsigned int*)l, 16, 0, 0);
}

// ---------------- block reduction helpers (256 threads = 4 waves) -----------
__device__ __forceinline__ float wave_sum(float v) {
#pragma unroll
  for (int o = 32; o; o >>= 1) v += __shfl_down(v, o, 64);
  return v;
}
__device__ __forceinline__ float block_sum(float v, float* s) {
  v = wave_sum(v);
  __syncthreads();
  if ((threadIdx.x & 63) == 0) s[threadIdx.x >> 6] = v;
  __syncthreads();
  return s[0] + s[1] + s[2] + s[3];
}

// ---------------- merged prep: cvt (prev/toks/W_proj) + all 4 transposes ----
// blocks [0, 26368): f32->bf16 convert, 4 elems/thread; block 0 zeroes rowsum
// blocks [26368, 33280): 32x32 transpose tiles (Wu, Wr, Wn -> bf16 T; Wp -> T)
__global__ __launch_bounds__(256) void k_prep(
    const float* __restrict__ prev, unsigned short* __restrict__ psb,
    const float* __restrict__ toks, unsigned short* __restrict__ tokb,
    const float* __restrict__ wp, unsigned short* __restrict__ wpb,
    const float* __restrict__ Wu, const float* __restrict__ Wr,
    const float* __restrict__ Wn,
    unsigned short* __restrict__ Wtur, unsigned short* __restrict__ Wtn,
    unsigned short* __restrict__ Wtp, float* __restrict__ rs) {
  __shared__ float tile[32][33];
  const int bid = blockIdx.x;
  if (bid < 26368) {
    if (bid == 0) {
      floatx4 z = {0.f, 0.f, 0.f, 0.f};
      *(floatx4*)(rs + threadIdx.x * 4) = z;
    }
    const long chunk = (long)bid * 256 + threadIdx.x;  // 4 elems per chunk
    const float* src;
    unsigned short* dst;
    long i;
    if (chunk < 262144) { src = prev; dst = psb; i = chunk * 4; }
    else if (chunk < 6553600) { src = toks; dst = tokb; i = (chunk - 262144) * 4; }
    else { src = wp; dst = wpb; i = (chunk - 6553600) * 4; }
    floatx4 v = *(const floatx4*)(src + i);
    unsigned short t4[4];
#pragma unroll
    for (int j = 0; j < 4; j++) t4[j] = f2b(v[j]);
    *(uint2*)(dst + i) = *(uint2*)t4;
    return;
  }
  // transpose part
  int t = bid - 26368;
  const float* in;
  unsigned short* out;
  int K, kx, ny;
  if (t < 6144) {  // 3 gate weights: each 64 x-blocks * 32 y-blocks
    const int which = t >> 11;  // /2048
    const int t2 = t & 2047;
    kx = t2 & 63;
    ny = t2 >> 6;
    K = 2048;
    in = which == 0 ? Wu : (which == 1 ? Wr : Wn);
    out = which == 0 ? Wtur : (which == 1 ? Wtur + 1024 * 2048 : Wtn);
  } else {  // W_proj: 24 x-blocks * 32 y-blocks
    const int t2 = t - 6144;
    kx = t2 % 24;
    ny = t2 / 24;
    K = 768;
    in = wp;
    out = Wtp;
  }
  const int N = 1024;
  const int k0 = kx * 32, n0 = ny * 32;
  const int tx = threadIdx.x & 31, ty = threadIdx.x >> 5;
#pragma unroll
  for (int i = 0; i < 32; i += 8)
    tile[ty + i][tx] = in[(long)(k0 + ty + i) * N + n0 + tx];
  __syncthreads();
#pragma unroll
  for (int i = 0; i < 32; i += 8)
    out[(long)(n0 + ty + i) * K + k0 + tx] = f2b(tile[tx][ty + i]);
}

// ---------------- 128x128 MFMA GEMM, BK=64, double-buffered, swizzled -------
// C[m][n] = A[m][k] * Bt[n][k]  (single batch)
// modes: 1: out2 bf16 = v
//        3: out f32  = (1-u)*prev + u*tanh(v+bias)
//        5: c<1024: out f32 = sigmoid(v+bias); else out2 bf16 = sigmoid(v+bias2)*psn
//        6: out f32 = v + aux_u[row]*bias2[c]
__global__ __launch_bounds__(256) void k_gemm128(
    const unsigned short* __restrict__ A, int lda,
    const unsigned short* __restrict__ Bt, int ldb,
    int K,
    const float* __restrict__ bias, const float* __restrict__ bias2,
    int mode,
    void* __restrict__ out, int ldc,
    unsigned short* __restrict__ out2,
    const unsigned short* __restrict__ aux_psn,
    const float* __restrict__ aux_u, const float* __restrict__ aux_prev) {
  __shared__ unsigned short As[2][128 * 64];
  __shared__ unsigned short Bs[2][128 * 64];
  const int tid = threadIdx.x;
  const int wave = tid >> 6, lane = tid & 63;
  const int m0 = blockIdx.x * 128, n0 = blockIdx.y * 128;
  const int wm = wave & 1, wn = wave >> 1;
  const int l16 = lane & 15, quad = lane >> 4;
  const int srow8 = lane >> 3;
  const int c8 = ((lane & 7) ^ srow8) * 8;

  const unsigned short* gA[4];
  const unsigned short* gB[4];
  int lOff[4];
#pragma unroll
  for (int j = 0; j < 4; j++) {
    const int rb = wave * 32 + j * 8;
    gA[j] = A + (long)(m0 + rb + srow8) * lda + c8;
    gB[j] = Bt + (long)(n0 + rb + srow8) * ldb + c8;
    lOff[j] = rb * 64;
  }
  int offA[2][4], offB[2][4];
#pragma unroll
  for (int ks = 0; ks < 2; ks++)
#pragma unroll
    for (int i = 0; i < 4; i++) {
      int r = wm * 64 + i * 16 + l16;
      offA[ks][i] = r * 64 + (((ks * 4 + quad) ^ (r & 7)) * 8);
      r = wn * 64 + i * 16 + l16;
      offB[ks][i] = r * 64 + (((ks * 4 + quad) ^ (r & 7)) * 8);
    }

  floatx4 acc[4][4] = {};

  // prologue: stage tile 0
#pragma unroll
  for (int j = 0; j < 4; j++) {
    g2l16(gA[j], &As[0][lOff[j]]);
    g2l16(gB[j], &Bs[0][lOff[j]]);
  }
  __syncthreads();

  const int nt = K >> 6;
  for (int t = 0; t < nt; t++) {
    const int cur = t & 1;
    if (t + 1 < nt) {
      const int kn = (t + 1) << 6;
#pragma unroll
      for (int j = 0; j < 4; j++) {
        g2l16(gA[j] + kn, &As[cur ^ 1][lOff[j]]);
        g2l16(gB[j] + kn, &Bs[cur ^ 1][lOff[j]]);
      }
    }
#pragma unroll
    for (int ks = 0; ks < 2; ks++) {
      shortx8 af[4], bf[4];
#pragma unroll
      for (int i = 0; i < 4; i++) af[i] = *(const shortx8*)&As[cur][offA[ks][i]];
#pragma unroll
      for (int j = 0; j < 4; j++) bf[j] = *(const shortx8*)&Bs[cur][offB[ks][j]];
#pragma unroll
      for (int i = 0; i < 4; i++)
#pragma unroll
        for (int j = 0; j < 4; j++)
          acc[i][j] = __builtin_amdgcn_mfma_f32_16x16x32_bf16(af[i], bf[j], acc[i][j], 0, 0, 0);
    }
    __syncthreads();  // drains next-tile loads (vmcnt(0)) + LDS handoff
  }

#pragma unroll
  for (int i = 0; i < 4; i++)
#pragma unroll
    for (int j = 0; j < 4; j++) {
      const int rbase = m0 + wm * 64 + i * 16 + quad * 4;
      const int c = n0 + wn * 64 + j * 16 + l16;
      float bval = 0.0f;
      if (bias) bval = (mode == 5 && c >= 1024) ? bias2[c - 1024] : bias[c];
#pragma unroll
      for (int r = 0; r < 4; r++) {
        const int row = rbase + r;
        float v = acc[i][j][r] + bval;
        if (mode == 1) {
          out2[(long)row * ldc + c] = f2b(v);
        } else if (mode == 3) {
          float cand = tanhf(v);
          float u = aux_u[(long)row * 1024 + c];
          float p = aux_prev[(long)row * 1024 + c];
          ((float*)out)[(long)row * ldc + c] = (1.0f - u) * p + u * cand;
        } else if (mode == 6) {
          ((float*)out)[(long)row * ldc + c] = v + aux_u[row] * bias2[c];
        } else {  // mode 5
          if (c < 1024) {
            ((float*)out)[(long)row * 1024 + c] = 1.0f / (1.0f + expf(-v));
          } else {
            const int cc = c - 1024;
            float rr = 1.0f / (1.0f + expf(-v));
            out2[(long)row * 2048 + cc] = f2b(rr * b2f(aux_psn[(long)row * 2048 + cc]));
          }
        }
      }
    }
}

// ---------------- scores: 64x64 MFMA GEMM, dbuf, exp epilogue + rowsum ------
// attnb[b][m][c] = exp(pw[b][m][:] . tok[b][c][:] * scale); rs += row sums
__global__ __launch_bounds__(256) void k_scores(
    const unsigned short* __restrict__ A, long sAb, int lda,
    const unsigned short* __restrict__ Bt, long sBb, int ldb,
    int K, float scale,
    unsigned short* __restrict__ out2, int ldc, long sCb,
    float* __restrict__ rs) {
  __shared__ unsigned short As[2][64 * 64];
  __shared__ unsigned short Bs[2][64 * 64];
  const int tid = threadIdx.x;
  const int wave = tid >> 6, lane = tid & 63;
  const int b = blockIdx.z;
  const int m0 = blockIdx.x * 64, n0 = blockIdx.y * 64;
  const int wm = wave & 1, wn = wave >> 1;
  const int l16 = lane & 15, quad = lane >> 4;
  const int srow8 = lane >> 3;
  const int c8 = ((lane & 7) ^ srow8) * 8;
  const unsigned short* Ab = A + (long)b * sAb;
  const unsigned short* Bb = Bt + (long)b * sBb;

  const unsigned short* gA[2];
  const unsigned short* gB[2];
  int lOff[2];
#pragma unroll
  for (int j = 0; j < 2; j++) {
    const int rb = wave * 16 + j * 8;
    gA[j] = Ab + (long)(m0 + rb + srow8) * lda + c8;
    gB[j] = Bb + (long)(n0 + rb + srow8) * ldb + c8;
    lOff[j] = rb * 64;
  }
  int offA[2][2], offB[2][2];
#pragma unroll
  for (int ks = 0; ks < 2; ks++)
#pragma unroll
    for (int i = 0; i < 2; i++) {
      int r = wm * 32 + i * 16 + l16;
      offA[ks][i] = r * 64 + (((ks * 4 + quad) ^ (r & 7)) * 8);
      r = wn * 32 + i * 16 + l16;
      offB[ks][i] = r * 64 + (((ks * 4 + quad) ^ (r & 7)) * 8);
    }

  floatx4 acc[2][2] = {};

#pragma unroll
  for (int j = 0; j < 2; j++) {
    g2l16(gA[j], &As[0][lOff[j]]);
    g2l16(gB[j], &Bs[0][lOff[j]]);
  }
  __syncthreads();

  const int nt = K >> 6;
  for (int t = 0; t < nt; t++) {
    const int cur = t & 1;
    if (t + 1 < nt) {
      const int kn = (t + 1) << 6;
#pragma unroll
      for (int j = 0; j < 2; j++) {
        g2l16(gA[j] + kn, &As[cur ^ 1][lOff[j]]);
        g2l16(gB[j] + kn, &Bs[cur ^ 1][lOff[j]]);
      }
    }
#pragma unroll
    for (int ks = 0; ks < 2; ks++) {
      shortx8 af[2], bf[2];
#pragma unroll
      for (int i = 0; i < 2; i++) af[i] = *(const shortx8*)&As[cur][offA[ks][i]];
#pragma unroll
      for (int j = 0; j < 2; j++) bf[j] = *(const shortx8*)&Bs[cur][offB[ks][j]];
#pragma unroll
      for (int i = 0; i < 2; i++)
#pragma unroll
        for (int j = 0; j < 2; j++)
          acc[i][j] = __builtin_amdgcn_mfma_f32_16x16x32_bf16(af[i], bf[j], acc[i][j], 0, 0, 0);
    }
    __syncthreads();
  }

#pragma unroll
  for (int i = 0; i < 2; i++) {
    float psum[4] = {0.f, 0.f, 0.f, 0.f};
#pragma unroll
    for (int j = 0; j < 2; j++) {
      const int rbase = m0 + wm * 32 + i * 16 + quad * 4;
      const int c = n0 + wn * 32 + j * 16 + l16;
#pragma unroll
      for (int r = 0; r < 4; r++) {
        const float e = expf(acc[i][j][r] * scale);
        out2[(long)b * sCb + (long)(rbase + r) * ldc + c] = f2b(e);
        psum[r] += e;
      }
    }
#pragma unroll
    for (int r = 0; r < 4; r++) {
      float s = psum[r];
      s += __shfl_xor(s, 1, 64);
      s += __shfl_xor(s, 2, 64);
      s += __shfl_xor(s, 4, 64);
      s += __shfl_xor(s, 8, 64);
      if (l16 == 0)
        atomicAdd(rs + (long)b * 64 + m0 + wm * 32 + i * 16 + quad * 4 + r, s);
    }
  }
}

// ---------------- rw = attnb(exp) @ tokens via MFMA -> bf16 -----------------
// attnb [16][64][2048] bf16, tokb [16][2048][768] bf16 -> rwb [1024][768] bf16
// async-STAGE: next-tile global loads stay in flight across raw barriers.
__global__ __launch_bounds__(256) void k_routed_mfma(
    const unsigned short* __restrict__ attnb,
    const unsigned short* __restrict__ tok,
    unsigned short* __restrict__ rwb) {
  __shared__ unsigned short As[64 * 40];
  __shared__ unsigned short Bs[32 * 66];
  const int nt = blockIdx.x, b = blockIdx.y;
  const int tid = threadIdx.x;
  const int wave = tid >> 6, lane = tid & 63;
  const int wm = wave & 1, wn = wave >> 1;
  const int l16 = lane & 15, quad = lane >> 4;
  const int n0 = nt * 64;
  const long abase = (long)b * 131072;
  const long tbase = (long)b * 1572864;
  const int srow = tid >> 2, skc = (tid & 3) * 8;
  const int bk = tid >> 3, bd = (tid & 7) * 8;

  floatx4 acc[2][2] = {};

  // prefetch tile 0 into registers
  uint4 pa = *(const uint4*)(attnb + abase + (long)srow * 2048 + skc);
  uint4 pb = *(const uint4*)(tok + tbase + (long)bk * 768 + n0 + bd);

  for (int k0 = 0; k0 < 2048; k0 += 32) {
    // write staged regs to LDS (compiler inserts the vmcnt wait here)
    *(uint4*)&As[srow * 40 + skc] = pa;
    {
      const unsigned* pv = (const unsigned*)&pb;
      unsigned short* dst = &Bs[bk * 66 + bd];
#pragma unroll
      for (int w2 = 0; w2 < 4; w2++) *(unsigned*)(dst + w2 * 2) = pv[w2];
    }
    // issue next-tile loads; they stay in flight across the barriers below
    if (k0 + 32 < 2048) {
      pa = *(const uint4*)(attnb + abase + (long)srow * 2048 + (k0 + 32) + skc);
      pb = *(const uint4*)(tok + tbase + (long)(k0 + 32 + bk) * 768 + n0 + bd);
    }
    asm volatile("s_waitcnt lgkmcnt(0)" ::: "memory");
    __builtin_amdgcn_s_barrier();
    __builtin_amdgcn_sched_barrier(0);

    shortx8 a0 = *(const shortx8*)&As[(wm * 32 + 0  + l16) * 40 + quad * 8];
    shortx8 a1 = *(const shortx8*)&As[(wm * 32 + 16 + l16) * 40 + quad * 8];
    shortx8 b0, b1;
#pragma unroll
    for (int j = 0; j < 8; j++) {
      b0[j] = *(const short*)&Bs[(quad * 8 + j) * 66 + wn * 32 + l16];
      b1[j] = *(const short*)&Bs[(quad * 8 + j) * 66 + wn * 32 + 16 + l16];
    }
    acc[0][0] = __builtin_amdgcn_mfma_f32_16x16x32_bf16(a0, b0, acc[0][0], 0, 0, 0);
    acc[0][1] = __builtin_amdgcn_mfma_f32_16x16x32_bf16(a0, b1, acc[0][1], 0, 0, 0);
    acc[1][0] = __builtin_amdgcn_mfma_f32_16x16x32_bf16(a1, b0, acc[1][0], 0, 0, 0);
    acc[1][1] = __builtin_amdgcn_mfma_f32_16x16x32_bf16(a1, b1, acc[1][1], 0, 0, 0);
    __builtin_amdgcn_s_barrier();  // all waves done reading LDS before overwrite
  }

#pragma unroll
  for (int im = 0; im < 2; im++)
#pragma unroll
    for (int in_ = 0; in_ < 2; in_++) {
      const int rbase = wm * 32 + im * 16 + quad * 4;
      const int c = n0 + wn * 32 + in_ * 16 + l16;
#pragma unroll
      for (int r = 0; r < 4; r++)
        rwb[((long)b * 64 + rbase + r) * 768 + c] = f2b(acc[im][in_][r]);
    }
}

// ---------------- merged LayerNorms: prev->conc[:, :D], routed->conc/candA --
__global__ __launch_bounds__(256) void k_ln2(
    const float* __restrict__ prev, const float* __restrict__ routed,
    const float* __restrict__ g_st, const float* __restrict__ be_st,
    const float* __restrict__ g_in, const float* __restrict__ be_in,
    unsigned short* __restrict__ conc, unsigned short* __restrict__ candA) {
  __shared__ float scr[4];
  const long r = blockIdx.x & 1023;
  const bool second = blockIdx.x >= 1024;
  const int t = threadIdx.x;
  floatx4 v;
  const float *g, *be;
  if (!second) {
    v = *(const floatx4*)(prev + r * 1024 + t * 4);
    g = g_st; be = be_st;
  } else {
    v = *(const floatx4*)(routed + r * 1024 + t * 4);
    g = g_in; be = be_in;
  }
  float s1 = v[0] + v[1] + v[2] + v[3];
  float s2 = v[0] * v[0] + v[1] * v[1] + v[2] * v[2] + v[3] * v[3];
  s1 = block_sum(s1, scr);
  s2 = block_sum(s2, scr);
  const float mean = s1 * (1.0f / 1024.0f);
  const float var = s2 * (1.0f / 1024.0f) - mean * mean;
  const float rstd = rsqrtf(var + LN_EPS);
#pragma unroll
  for (int i = 0; i < 4; i++) {
    const int d = t * 4 + i;
    const float y = (v[i] - mean) * rstd * g[d] + be[d];
    const unsigned short h = f2b(y);
    if (!second) {
      conc[r * 2048 + d] = h;
    } else {
      conc[r * 2048 + 1024 + d] = h;
      candA[r * 2048 + 1024 + d] = h;
    }
  }
}

// ---------------- final LayerNorm -> f32 output ------------------------------
__global__ __launch_bounds__(256) void k_ln_out(
    const float* __restrict__ in, const float* __restrict__ g,
    const float* __restrict__ be, float* __restrict__ out) {
  __shared__ float scr[4];
  const long r = blockIdx.x;
  const int t = threadIdx.x;
  floatx4 v = *(const floatx4*)(in + r * 1024 + t * 4);
  float s1 = v[0] + v[1] + v[2] + v[3];
  float s2 = v[0] * v[0] + v[1] * v[1] + v[2] * v[2] + v[3] * v[3];
  s1 = block_sum(s1, scr);
  s2 = block_sum(s2, scr);
  const float mean = s1 * (1.0f / 1024.0f);
  const float var = s2 * (1.0f / 1024.0f) - mean * mean;
  const float rstd = rsqrtf(var + LN_EPS);
  floatx4 o;
#pragma unroll
  for (int i = 0; i < 4; i++) {
    const int d = t * 4 + i;
    o[i] = (v[i] - mean) * rstd * g[d] + be[d];
  }
  *(floatx4*)(out + r * 1024 + t * 4) = o;
}

// ---------------------------------------------------------------------------
extern "C" void kernel_launch(void* const* d_in, const int* in_sizes, int n_in,
                              void* d_out, int out_size, void* d_ws, size_t ws_size,
                              hipStream_t stream) {
  (void)in_sizes; (void)n_in; (void)out_size; (void)ws_size;
  const float* prev  = (const float*)d_in[0];
  const float* toks  = (const float*)d_in[1];
  const float* Wp    = (const float*)d_in[2];
  const float* bp    = (const float*)d_in[3];
  const float* g_st  = (const float*)d_in[4];
  const float* be_st = (const float*)d_in[5];
  const float* g_in  = (const float*)d_in[6];
  const float* be_in = (const float*)d_in[7];
  const float* g_o   = (const float*)d_in[8];
  const float* be_o  = (const float*)d_in[9];
  const float* Wu    = (const float*)d_in[10];
  const float* bu    = (const float*)d_in[11];
  const float* Wr    = (const float*)d_in[12];
  const float* br    = (const float*)d_in[13];
  const float* Wn    = (const float*)d_in[14];
  const float* bn    = (const float*)d_in[15];
  float* out = (float*)d_out;

  // ---- workspace (~97 MB)
  char* ws = (char*)d_ws;
  unsigned short* tokb  = (unsigned short*)ws; ws += 50331648;  // 32768x768 bf16
  unsigned short* psb   = (unsigned short*)ws; ws += 2097152;   // 1024x1024 bf16
  unsigned short* Wpb   = (unsigned short*)ws; ws += 1572864;   // 768x1024 bf16
  unsigned short* Wtp   = (unsigned short*)ws; ws += 1572864;   // 1024x768 bf16
  unsigned short* pwb   = (unsigned short*)ws; ws += 1572864;   // 1024x768 bf16
  unsigned short* attnb = (unsigned short*)ws; ws += 4194304;   // 16x64x2048 bf16
  float*          rowsum= (float*)ws;          ws += 4096;      // 1024 f32
  unsigned short* rwb   = (unsigned short*)ws; ws += 1572864;   // 1024x768 bf16
  float*          routed= (float*)ws;          ws += 4194304;   // 1024x1024 f32
  unsigned short* conc  = (unsigned short*)ws; ws += 4194304;   // 1024x2048 bf16
  unsigned short* candA = (unsigned short*)ws; ws += 4194304;   // 1024x2048 bf16
  float*          ubuf  = (float*)ws;          ws += 4194304;   // 1024x1024 f32
  float*          ns    = (float*)ws;          ws += 4194304;   // 1024x1024 f32
  unsigned short* Wtur  = (unsigned short*)ws; ws += 8388608;   // 2048x2048 bf16
  unsigned short* Wtn   = (unsigned short*)ws; ws += 4194304;   // 1024x2048 bf16

  const dim3 blk(256);

  // 1. merged prep: converts + transposes + rowsum zero
  k_prep<<<dim3(33280), blk, 0, stream>>>(prev, psb, toks, tokb, Wp, Wpb,
                                          Wu, Wr, Wn, Wtur, Wtn, Wtp, rowsum);
  // 2. pw = prev @ W_proj^T  (M=1024, N=768, K=1024) -> bf16 (mode 1)
  k_gemm128<<<dim3(8, 6), blk, 0, stream>>>(
      psb, 1024, Wpb, 1024, 1024,
      nullptr, nullptr, 1,
      nullptr, 768, pwb, nullptr, nullptr, nullptr);
  // 3. attnb = exp(pw @ tokens^T / 32) + fused rowsum atomics
  k_scores<<<dim3(1, 32, 16), blk, 0, stream>>>(
      pwb, 49152L, 768, tokb, 1572864L, 768, 768, 0.03125f,
      attnb, 2048, 131072L, rowsum);
  // 4. rw = w @ tokens (unnormalized) -> bf16
  k_routed_mfma<<<dim3(12, 16), blk, 0, stream>>>(attnb, tokb, rwb);
  // 5. routed = rw @ W_proj + rowsum*b_proj  (M=1024, N=1024, K=768, mode 6)
  k_gemm128<<<dim3(8, 8), blk, 0, stream>>>(
      rwb, 768, Wtp, 768, 768,
      nullptr, bp, 6,
      (void*)routed, 1024, nullptr, nullptr, rowsum, nullptr);
  // 6. both LayerNorms
  k_ln2<<<dim3(2048), blk, 0, stream>>>(prev, routed, g_st, be_st, g_in, be_in,
                                        conc, candA);
  // 7. merged u|r gates (mode 5)
  k_gemm128<<<dim3(8, 16), blk, 0, stream>>>(
      conc, 2048, Wtur, 2048, 2048,
      bu, br, 5,
      (void*)ubuf, 1024, candA, conc, nullptr, nullptr);
  // 8. new_state (mode 3)
  k_gemm128<<<dim3(8, 8), blk, 0, stream>>>(
      candA, 2048, Wtn, 2048, 2048,
      bn, nullptr, 3,
      (void*)ns, 1024, nullptr, nullptr, ubuf, prev);
  // 9. final LN -> output
  k_ln_out<<<dim3(1024), blk, 0, stream>>>(ns, g_o, be_o, out);
}

// Round 4
// 337.267 us; speedup vs baseline: 1.2819x; 1.2819x over previous
//
#include <hip/hip_runtime.h>
#include <stdint.h>

typedef __attribute__((ext_vector_type(4))) float floatx4;
typedef __attribute__((ext_vector_type(8))) short shortx8;

#define LN_EPS 1e-5f

__device__ __forceinline__ unsigned short f2b(float f) {
  unsigned u = __builtin_bit_cast(unsigned, f);
  u = (u + 0x7FFFu + ((u >> 16) & 1u)) >> 16;
  return (unsigned short)u;
}
__device__ __forceinline__ float b2f(unsigned short h) {
  return __builtin_bit_cast(float, (unsigned)h << 16);
}

// async global->LDS 16B: lds dest is wave-uniform base; lane i lands at base + i*16
__device__ __forceinline__ void g2l16(const unsigned short* g, unsigned short* l) {
  __builtin_amdgcn_global_load_lds(
      (const __attribute__((address_space(1))) unsigned int*)g,
      (__attribute__((address_space(3))) unsigned int*)l, 16, 0, 0);
}

// ---------------- block reduction helpers (256 threads = 4 waves) -----------
__device__ __forceinline__ float wave_sum(float v) {
#pragma unroll
  for (int o = 32; o; o >>= 1) v += __shfl_down(v, o, 64);
  return v;
}
__device__ __forceinline__ float block_sum(float v, float* s) {
  v = wave_sum(v);
  __syncthreads();
  if ((threadIdx.x & 63) == 0) s[threadIdx.x >> 6] = v;
  __syncthreads();
  return s[0] + s[1] + s[2] + s[3];
}

// ---------------- merged prep: cvt (prev/toks/W_proj) + all 4 transposes ----
// blocks [0, 26368): f32->bf16 convert, 4 elems/thread; block 0 zeroes rowsum
// blocks [26368, 33280): 32x32 transpose tiles (Wu, Wr, Wn -> bf16 T; Wp -> T)
__global__ __launch_bounds__(256) void k_prep(
    const float* __restrict__ prev, unsigned short* __restrict__ psb,
    const float* __restrict__ toks, unsigned short* __restrict__ tokb,
    const float* __restrict__ wp, unsigned short* __restrict__ wpb,
    const float* __restrict__ Wu, const float* __restrict__ Wr,
    const float* __restrict__ Wn,
    unsigned short* __restrict__ Wtur, unsigned short* __restrict__ Wtn,
    unsigned short* __restrict__ Wtp, float* __restrict__ rs) {
  __shared__ float tile[32][33];
  const int bid = blockIdx.x;
  if (bid < 26368) {
    if (bid == 0) {
      floatx4 z = {0.f, 0.f, 0.f, 0.f};
      *(floatx4*)(rs + threadIdx.x * 4) = z;
    }
    const long chunk = (long)bid * 256 + threadIdx.x;  // 4 elems per chunk
    const float* src;
    unsigned short* dst;
    long i;
    if (chunk < 262144) { src = prev; dst = psb; i = chunk * 4; }
    else if (chunk < 6553600) { src = toks; dst = tokb; i = (chunk - 262144) * 4; }
    else { src = wp; dst = wpb; i = (chunk - 6553600) * 4; }
    floatx4 v = *(const floatx4*)(src + i);
    unsigned short t4[4];
#pragma unroll
    for (int j = 0; j < 4; j++) t4[j] = f2b(v[j]);
    *(uint2*)(dst + i) = *(uint2*)t4;
    return;
  }
  // transpose part
  int t = bid - 26368;
  const float* in;
  unsigned short* out;
  int K, kx, ny;
  if (t < 6144) {  // 3 gate weights: each 64 x-blocks * 32 y-blocks
    const int which = t >> 11;  // /2048
    const int t2 = t & 2047;
    kx = t2 & 63;
    ny = t2 >> 6;
    K = 2048;
    in = which == 0 ? Wu : (which == 1 ? Wr : Wn);
    out = which == 0 ? Wtur : (which == 1 ? Wtur + 1024 * 2048 : Wtn);
  } else {  // W_proj: 24 x-blocks * 32 y-blocks
    const int t2 = t - 6144;
    kx = t2 % 24;
    ny = t2 / 24;
    K = 768;
    in = wp;
    out = Wtp;
  }
  const int N = 1024;
  const int k0 = kx * 32, n0 = ny * 32;
  const int tx = threadIdx.x & 31, ty = threadIdx.x >> 5;
#pragma unroll
  for (int i = 0; i < 32; i += 8)
    tile[ty + i][tx] = in[(long)(k0 + ty + i) * N + n0 + tx];
  __syncthreads();
#pragma unroll
  for (int i = 0; i < 32; i += 8)
    out[(long)(n0 + ty + i) * K + k0 + tx] = f2b(tile[tx][ty + i]);
}

// ---------------- 64x64 MFMA GEMM, BK=64, double-buffered, XCD-swizzled -----
// C[m][n] = A[m][k] * Bt[n][k]  (single matrix, no batch)
// Bijective XCD swizzle: requires gridDim.x*gridDim.y % 8 == 0. XCD k owns a
// contiguous chunk of flat work ids -> B-panel re-reads hit that XCD's L2.
// modes: 1: out2 bf16 = v
//        3: out f32  = (1-u)*prev + u*tanh(v+bias)
//        5: c<1024: out f32 = sigmoid(v+bias); else out2 bf16 = sigmoid(v+bias2)*psn
//        6: out f32 = v + aux_u[row]*bias2[c]
__global__ __launch_bounds__(256) void k_gemm64(
    const unsigned short* __restrict__ A, int lda,
    const unsigned short* __restrict__ Bt, int ldb,
    int K,
    const float* __restrict__ bias, const float* __restrict__ bias2,
    int mode,
    void* __restrict__ out, int ldc,
    unsigned short* __restrict__ out2,
    const unsigned short* __restrict__ aux_psn,
    const float* __restrict__ aux_u, const float* __restrict__ aux_prev) {
  __shared__ unsigned short As[2][64 * 64];
  __shared__ unsigned short Bs[2][64 * 64];
  const int tid = threadIdx.x;
  const int wave = tid >> 6, lane = tid & 63;
  // XCD-aware bijective work remap
  const int flat = blockIdx.x + blockIdx.y * gridDim.x;
  const int q = (gridDim.x * gridDim.y) >> 3;
  const int swz = (flat & 7) * q + (flat >> 3);
  const int m0 = (swz % gridDim.x) * 64;
  const int n0 = (swz / gridDim.x) * 64;
  const int wm = wave & 1, wn = wave >> 1;
  const int l16 = lane & 15, quad = lane >> 4;
  const int srow8 = lane >> 3;
  const int c8 = ((lane & 7) ^ srow8) * 8;

  const unsigned short* gA[2];
  const unsigned short* gB[2];
  int lOff[2];
#pragma unroll
  for (int j = 0; j < 2; j++) {
    const int rb = wave * 16 + j * 8;
    gA[j] = A + (long)(m0 + rb + srow8) * lda + c8;
    gB[j] = Bt + (long)(n0 + rb + srow8) * ldb + c8;
    lOff[j] = rb * 64;
  }
  int offA[2][2], offB[2][2];
#pragma unroll
  for (int ks = 0; ks < 2; ks++)
#pragma unroll
    for (int i = 0; i < 2; i++) {
      int r = wm * 32 + i * 16 + l16;
      offA[ks][i] = r * 64 + (((ks * 4 + quad) ^ (r & 7)) * 8);
      r = wn * 32 + i * 16 + l16;
      offB[ks][i] = r * 64 + (((ks * 4 + quad) ^ (r & 7)) * 8);
    }

  floatx4 acc[2][2] = {};

  // prologue: stage tile 0 into buffer 0
#pragma unroll
  for (int j = 0; j < 2; j++) {
    g2l16(gA[j], &As[0][lOff[j]]);
    g2l16(gB[j], &Bs[0][lOff[j]]);
  }
  __syncthreads();

  const int nt = K >> 6;
  for (int t = 0; t < nt; t++) {
    const int cur = t & 1;
    if (t + 1 < nt) {
      const int kn = (t + 1) << 6;
#pragma unroll
      for (int j = 0; j < 2; j++) {
        g2l16(gA[j] + kn, &As[cur ^ 1][lOff[j]]);
        g2l16(gB[j] + kn, &Bs[cur ^ 1][lOff[j]]);
      }
    }
#pragma unroll
    for (int ks = 0; ks < 2; ks++) {
      shortx8 af[2], bf[2];
#pragma unroll
      for (int i = 0; i < 2; i++) af[i] = *(const shortx8*)&As[cur][offA[ks][i]];
#pragma unroll
      for (int j = 0; j < 2; j++) bf[j] = *(const shortx8*)&Bs[cur][offB[ks][j]];
#pragma unroll
      for (int i = 0; i < 2; i++)
#pragma unroll
        for (int j = 0; j < 2; j++)
          acc[i][j] = __builtin_amdgcn_mfma_f32_16x16x32_bf16(af[i], bf[j], acc[i][j], 0, 0, 0);
    }
    __syncthreads();  // implicit vmcnt(0): drains next-tile loads issued above
  }

#pragma unroll
  for (int i = 0; i < 2; i++)
#pragma unroll
    for (int j = 0; j < 2; j++) {
      const int rbase = m0 + wm * 32 + i * 16 + quad * 4;
      const int c = n0 + wn * 32 + j * 16 + l16;
      float bval = 0.0f;
      if (bias) bval = (mode == 5 && c >= 1024) ? bias2[c - 1024] : bias[c];
#pragma unroll
      for (int r = 0; r < 4; r++) {
        const int row = rbase + r;
        float v = acc[i][j][r] + bval;
        if (mode == 1) {
          out2[(long)row * ldc + c] = f2b(v);
        } else if (mode == 3) {
          float cand = tanhf(v);
          float u = aux_u[(long)row * 1024 + c];
          float p = aux_prev[(long)row * 1024 + c];
          ((float*)out)[(long)row * ldc + c] = (1.0f - u) * p + u * cand;
        } else if (mode == 6) {
          ((float*)out)[(long)row * ldc + c] = v + aux_u[row] * bias2[c];
        } else {  // mode 5
          if (c < 1024) {
            ((float*)out)[(long)row * 1024 + c] = 1.0f / (1.0f + expf(-v));
          } else {
            const int cc = c - 1024;
            float rr = 1.0f / (1.0f + expf(-v));
            out2[(long)row * 2048 + cc] = f2b(rr * b2f(aux_psn[(long)row * 2048 + cc]));
          }
        }
      }
    }
}

// ---------------- scores: 64x64 MFMA GEMM, dbuf, exp epilogue + rowsum ------
// attnb[b][m][c] = exp(pw[b][m][:] . tok[b][c][:] * scale); rs += row sums
__global__ __launch_bounds__(256) void k_scores(
    const unsigned short* __restrict__ A, long sAb, int lda,
    const unsigned short* __restrict__ Bt, long sBb, int ldb,
    int K, float scale,
    unsigned short* __restrict__ out2, int ldc, long sCb,
    float* __restrict__ rs) {
  __shared__ unsigned short As[2][64 * 64];
  __shared__ unsigned short Bs[2][64 * 64];
  const int tid = threadIdx.x;
  const int wave = tid >> 6, lane = tid & 63;
  const int b = blockIdx.z;
  const int m0 = blockIdx.x * 64, n0 = blockIdx.y * 64;
  const int wm = wave & 1, wn = wave >> 1;
  const int l16 = lane & 15, quad = lane >> 4;
  const int srow8 = lane >> 3;
  const int c8 = ((lane & 7) ^ srow8) * 8;
  const unsigned short* Ab = A + (long)b * sAb;
  const unsigned short* Bb = Bt + (long)b * sBb;

  const unsigned short* gA[2];
  const unsigned short* gB[2];
  int lOff[2];
#pragma unroll
  for (int j = 0; j < 2; j++) {
    const int rb = wave * 16 + j * 8;
    gA[j] = Ab + (long)(m0 + rb + srow8) * lda + c8;
    gB[j] = Bb + (long)(n0 + rb + srow8) * ldb + c8;
    lOff[j] = rb * 64;
  }
  int offA[2][2], offB[2][2];
#pragma unroll
  for (int ks = 0; ks < 2; ks++)
#pragma unroll
    for (int i = 0; i < 2; i++) {
      int r = wm * 32 + i * 16 + l16;
      offA[ks][i] = r * 64 + (((ks * 4 + quad) ^ (r & 7)) * 8);
      r = wn * 32 + i * 16 + l16;
      offB[ks][i] = r * 64 + (((ks * 4 + quad) ^ (r & 7)) * 8);
    }

  floatx4 acc[2][2] = {};

#pragma unroll
  for (int j = 0; j < 2; j++) {
    g2l16(gA[j], &As[0][lOff[j]]);
    g2l16(gB[j], &Bs[0][lOff[j]]);
  }
  __syncthreads();

  const int nt = K >> 6;
  for (int t = 0; t < nt; t++) {
    const int cur = t & 1;
    if (t + 1 < nt) {
      const int kn = (t + 1) << 6;
#pragma unroll
      for (int j = 0; j < 2; j++) {
        g2l16(gA[j] + kn, &As[cur ^ 1][lOff[j]]);
        g2l16(gB[j] + kn, &Bs[cur ^ 1][lOff[j]]);
      }
    }
#pragma unroll
    for (int ks = 0; ks < 2; ks++) {
      shortx8 af[2], bf[2];
#pragma unroll
      for (int i = 0; i < 2; i++) af[i] = *(const shortx8*)&As[cur][offA[ks][i]];
#pragma unroll
      for (int j = 0; j < 2; j++) bf[j] = *(const shortx8*)&Bs[cur][offB[ks][j]];
#pragma unroll
      for (int i = 0; i < 2; i++)
#pragma unroll
        for (int j = 0; j < 2; j++)
          acc[i][j] = __builtin_amdgcn_mfma_f32_16x16x32_bf16(af[i], bf[j], acc[i][j], 0, 0, 0);
    }
    __syncthreads();
  }

#pragma unroll
  for (int i = 0; i < 2; i++) {
    float psum[4] = {0.f, 0.f, 0.f, 0.f};
#pragma unroll
    for (int j = 0; j < 2; j++) {
      const int rbase = m0 + wm * 32 + i * 16 + quad * 4;
      const int c = n0 + wn * 32 + j * 16 + l16;
#pragma unroll
      for (int r = 0; r < 4; r++) {
        const float e = expf(acc[i][j][r] * scale);
        out2[(long)b * sCb + (long)(rbase + r) * ldc + c] = f2b(e);
        psum[r] += e;
      }
    }
#pragma unroll
    for (int r = 0; r < 4; r++) {
      float s = psum[r];
      s += __shfl_xor(s, 1, 64);
      s += __shfl_xor(s, 2, 64);
      s += __shfl_xor(s, 4, 64);
      s += __shfl_xor(s, 8, 64);
      if (l16 == 0)
        atomicAdd(rs + (long)b * 64 + m0 + wm * 32 + i * 16 + quad * 4 + r, s);
    }
  }
}

// ---------------- rw = attnb(exp) @ tokens via MFMA -> bf16 -----------------
// attnb [16][64][2048] bf16, tokb [16][2048][768] bf16 -> rwb [1024][768] bf16
// async-STAGE: next-tile global loads stay in flight across raw barriers.
__global__ __launch_bounds__(256) void k_routed_mfma(
    const unsigned short* __restrict__ attnb,
    const unsigned short* __restrict__ tok,
    unsigned short* __restrict__ rwb) {
  __shared__ unsigned short As[64 * 40];
  __shared__ unsigned short Bs[32 * 66];
  const int nt = blockIdx.x, b = blockIdx.y;
  const int tid = threadIdx.x;
  const int wave = tid >> 6, lane = tid & 63;
  const int wm = wave & 1, wn = wave >> 1;
  const int l16 = lane & 15, quad = lane >> 4;
  const int n0 = nt * 64;
  const long abase = (long)b * 131072;
  const long tbase = (long)b * 1572864;
  const int srow = tid >> 2, skc = (tid & 3) * 8;
  const int bk = tid >> 3, bd = (tid & 7) * 8;

  floatx4 acc[2][2] = {};

  // prefetch tile 0 into registers
  uint4 pa = *(const uint4*)(attnb + abase + (long)srow * 2048 + skc);
  uint4 pb = *(const uint4*)(tok + tbase + (long)bk * 768 + n0 + bd);

  for (int k0 = 0; k0 < 2048; k0 += 32) {
    // write staged regs to LDS (compiler inserts the vmcnt wait here)
    *(uint4*)&As[srow * 40 + skc] = pa;
    {
      const unsigned* pv = (const unsigned*)&pb;
      unsigned short* dst = &Bs[bk * 66 + bd];
#pragma unroll
      for (int w2 = 0; w2 < 4; w2++) *(unsigned*)(dst + w2 * 2) = pv[w2];
    }
    // issue next-tile loads; they stay in flight across the barriers below
    if (k0 + 32 < 2048) {
      pa = *(const uint4*)(attnb + abase + (long)srow * 2048 + (k0 + 32) + skc);
      pb = *(const uint4*)(tok + tbase + (long)(k0 + 32 + bk) * 768 + n0 + bd);
    }
    asm volatile("s_waitcnt lgkmcnt(0)" ::: "memory");
    __builtin_amdgcn_s_barrier();
    __builtin_amdgcn_sched_barrier(0);

    shortx8 a0 = *(const shortx8*)&As[(wm * 32 + 0  + l16) * 40 + quad * 8];
    shortx8 a1 = *(const shortx8*)&As[(wm * 32 + 16 + l16) * 40 + quad * 8];
    shortx8 b0, b1;
#pragma unroll
    for (int j = 0; j < 8; j++) {
      b0[j] = *(const short*)&Bs[(quad * 8 + j) * 66 + wn * 32 + l16];
      b1[j] = *(const short*)&Bs[(quad * 8 + j) * 66 + wn * 32 + 16 + l16];
    }
    acc[0][0] = __builtin_amdgcn_mfma_f32_16x16x32_bf16(a0, b0, acc[0][0], 0, 0, 0);
    acc[0][1] = __builtin_amdgcn_mfma_f32_16x16x32_bf16(a0, b1, acc[0][1], 0, 0, 0);
    acc[1][0] = __builtin_amdgcn_mfma_f32_16x16x32_bf16(a1, b0, acc[1][0], 0, 0, 0);
    acc[1][1] = __builtin_amdgcn_mfma_f32_16x16x32_bf16(a1, b1, acc[1][1], 0, 0, 0);
    __builtin_amdgcn_s_barrier();  // all waves done reading LDS before overwrite
  }

#pragma unroll
  for (int im = 0; im < 2; im++)
#pragma unroll
    for (int in_ = 0; in_ < 2; in_++) {
      const int rbase = wm * 32 + im * 16 + quad * 4;
      const int c = n0 + wn * 32 + in_ * 16 + l16;
#pragma unroll
      for (int r = 0; r < 4; r++)
        rwb[((long)b * 64 + rbase + r) * 768 + c] = f2b(acc[im][in_][r]);
    }
}

// ---------------- merged LayerNorms: prev->conc[:, :D], routed->conc/candA --
__global__ __launch_bounds__(256) void k_ln2(
    const float* __restrict__ prev, const float* __restrict__ routed,
    const float* __restrict__ g_st, const float* __restrict__ be_st,
    const float* __restrict__ g_in, const float* __restrict__ be_in,
    unsigned short* __restrict__ conc, unsigned short* __restrict__ candA) {
  __shared__ float scr[4];
  const long r = blockIdx.x & 1023;
  const bool second = blockIdx.x >= 1024;
  const int t = threadIdx.x;
  floatx4 v;
  const float *g, *be;
  if (!second) {
    v = *(const floatx4*)(prev + r * 1024 + t * 4);
    g = g_st; be = be_st;
  } else {
    v = *(const floatx4*)(routed + r * 1024 + t * 4);
    g = g_in; be = be_in;
  }
  float s1 = v[0] + v[1] + v[2] + v[3];
  float s2 = v[0] * v[0] + v[1] * v[1] + v[2] * v[2] + v[3] * v[3];
  s1 = block_sum(s1, scr);
  s2 = block_sum(s2, scr);
  const float mean = s1 * (1.0f / 1024.0f);
  const float var = s2 * (1.0f / 1024.0f) - mean * mean;
  const float rstd = rsqrtf(var + LN_EPS);
#pragma unroll
  for (int i = 0; i < 4; i++) {
    const int d = t * 4 + i;
    const float y = (v[i] - mean) * rstd * g[d] + be[d];
    const unsigned short h = f2b(y);
    if (!second) {
      conc[r * 2048 + d] = h;
    } else {
      conc[r * 2048 + 1024 + d] = h;
      candA[r * 2048 + 1024 + d] = h;
    }
  }
}

// ---------------- final LayerNorm -> f32 output ------------------------------
__global__ __launch_bounds__(256) void k_ln_out(
    const float* __restrict__ in, const float* __restrict__ g,
    const float* __restrict__ be, float* __restrict__ out) {
  __shared__ float scr[4];
  const long r = blockIdx.x;
  const int t = threadIdx.x;
  floatx4 v = *(const floatx4*)(in + r * 1024 + t * 4);
  float s1 = v[0] + v[1] + v[2] + v[3];
  float s2 = v[0] * v[0] + v[1] * v[1] + v[2] * v[2] + v[3] * v[3];
  s1 = block_sum(s1, scr);
  s2 = block_sum(s2, scr);
  const float mean = s1 * (1.0f / 1024.0f);
  const float var = s2 * (1.0f / 1024.0f) - mean * mean;
  const float rstd = rsqrtf(var + LN_EPS);
  floatx4 o;
#pragma unroll
  for (int i = 0; i < 4; i++) {
    const int d = t * 4 + i;
    o[i] = (v[i] - mean) * rstd * g[d] + be[d];
  }
  *(floatx4*)(out + r * 1024 + t * 4) = o;
}

// ---------------------------------------------------------------------------
extern "C" void kernel_launch(void* const* d_in, const int* in_sizes, int n_in,
                              void* d_out, int out_size, void* d_ws, size_t ws_size,
                              hipStream_t stream) {
  (void)in_sizes; (void)n_in; (void)out_size; (void)ws_size;
  const float* prev  = (const float*)d_in[0];
  const float* toks  = (const float*)d_in[1];
  const float* Wp    = (const float*)d_in[2];
  const float* bp    = (const float*)d_in[3];
  const float* g_st  = (const float*)d_in[4];
  const float* be_st = (const float*)d_in[5];
  const float* g_in  = (const float*)d_in[6];
  const float* be_in = (const float*)d_in[7];
  const float* g_o   = (const float*)d_in[8];
  const float* be_o  = (const float*)d_in[9];
  const float* Wu    = (const float*)d_in[10];
  const float* bu    = (const float*)d_in[11];
  const float* Wr    = (const float*)d_in[12];
  const float* br    = (const float*)d_in[13];
  const float* Wn    = (const float*)d_in[14];
  const float* bn    = (const float*)d_in[15];
  float* out = (float*)d_out;

  // ---- workspace (~97 MB)
  char* ws = (char*)d_ws;
  unsigned short* tokb  = (unsigned short*)ws; ws += 50331648;  // 32768x768 bf16
  unsigned short* psb   = (unsigned short*)ws; ws += 2097152;   // 1024x1024 bf16
  unsigned short* Wpb   = (unsigned short*)ws; ws += 1572864;   // 768x1024 bf16
  unsigned short* Wtp   = (unsigned short*)ws; ws += 1572864;   // 1024x768 bf16
  unsigned short* pwb   = (unsigned short*)ws; ws += 1572864;   // 1024x768 bf16
  unsigned short* attnb = (unsigned short*)ws; ws += 4194304;   // 16x64x2048 bf16
  float*          rowsum= (float*)ws;          ws += 4096;      // 1024 f32
  unsigned short* rwb   = (unsigned short*)ws; ws += 1572864;   // 1024x768 bf16
  float*          routed= (float*)ws;          ws += 4194304;   // 1024x1024 f32
  unsigned short* conc  = (unsigned short*)ws; ws += 4194304;   // 1024x2048 bf16
  unsigned short* candA = (unsigned short*)ws; ws += 4194304;   // 1024x2048 bf16
  float*          ubuf  = (float*)ws;          ws += 4194304;   // 1024x1024 f32
  float*          ns    = (float*)ws;          ws += 4194304;   // 1024x1024 f32
  unsigned short* Wtur  = (unsigned short*)ws; ws += 8388608;   // 2048x2048 bf16
  unsigned short* Wtn   = (unsigned short*)ws; ws += 4194304;   // 1024x2048 bf16

  const dim3 blk(256);

  // 1. merged prep: converts + transposes + rowsum zero
  k_prep<<<dim3(33280), blk, 0, stream>>>(prev, psb, toks, tokb, Wp, Wpb,
                                          Wu, Wr, Wn, Wtur, Wtn, Wtp, rowsum);
  // 2. pw = prev @ W_proj^T  (M=1024, N=768, K=1024) -> bf16 (mode 1), 192 blocks
  k_gemm64<<<dim3(16, 12), blk, 0, stream>>>(
      psb, 1024, Wpb, 1024, 1024,
      nullptr, nullptr, 1,
      nullptr, 768, pwb, nullptr, nullptr, nullptr);
  // 3. attnb = exp(pw @ tokens^T / 32) + fused rowsum atomics, 512 blocks
  k_scores<<<dim3(1, 32, 16), blk, 0, stream>>>(
      pwb, 49152L, 768, tokb, 1572864L, 768, 768, 0.03125f,
      attnb, 2048, 131072L, rowsum);
  // 4. rw = w @ tokens (unnormalized) -> bf16, 192 blocks
  k_routed_mfma<<<dim3(12, 16), blk, 0, stream>>>(attnb, tokb, rwb);
  // 5. routed = rw @ W_proj + rowsum*b_proj  (M=1024, N=1024, K=768, mode 6), 256 blocks
  k_gemm64<<<dim3(16, 16), blk, 0, stream>>>(
      rwb, 768, Wtp, 768, 768,
      nullptr, bp, 6,
      (void*)routed, 1024, nullptr, nullptr, rowsum, nullptr);
  // 6. both LayerNorms
  k_ln2<<<dim3(2048), blk, 0, stream>>>(prev, routed, g_st, be_st, g_in, be_in,
                                        conc, candA);
  // 7. merged u|r gates (mode 5), 512 blocks
  k_gemm64<<<dim3(16, 32), blk, 0, stream>>>(
      conc, 2048, Wtur, 2048, 2048,
      bu, br, 5,
      (void*)ubuf, 1024, candA, conc, nullptr, nullptr);
  // 8. new_state (mode 3), 256 blocks
  k_gemm64<<<dim3(16, 16), blk, 0, stream>>>(
      candA, 2048, Wtn, 2048, 2048,
      bn, nullptr, 3,
      (void*)ns, 1024, nullptr, nullptr, ubuf, prev);
  // 9. final LN -> output
  k_ln_out<<<dim3(1024), blk, 0, stream>>>(ns, g_o, be_o, out);
}

// Round 5
// 322.221 us; speedup vs baseline: 1.3418x; 1.0467x over previous
//
#include <hip/hip_runtime.h>
#include <stdint.h>

typedef __attribute__((ext_vector_type(4))) float floatx4;
typedef __attribute__((ext_vector_type(8))) short shortx8;

#define LN_EPS 1e-5f

__device__ __forceinline__ unsigned short f2b(float f) {
  unsigned u = __builtin_bit_cast(unsigned, f);
  u = (u + 0x7FFFu + ((u >> 16) & 1u)) >> 16;
  return (unsigned short)u;
}
__device__ __forceinline__ float b2f(unsigned short h) {
  return __builtin_bit_cast(float, (unsigned)h << 16);
}

// async global->LDS 16B: lds dest is wave-uniform base; lane i lands at base + i*16
__device__ __forceinline__ void g2l16(const unsigned short* g, unsigned short* l) {
  __builtin_amdgcn_global_load_lds(
      (const __attribute__((address_space(1))) unsigned int*)g,
      (__attribute__((address_space(3))) unsigned int*)l, 16, 0, 0);
}

// ---------------- block reduction helpers (256 threads = 4 waves) -----------
__device__ __forceinline__ float wave_sum(float v) {
#pragma unroll
  for (int o = 32; o; o >>= 1) v += __shfl_down(v, o, 64);
  return v;
}
__device__ __forceinline__ float block_sum(float v, float* s) {
  v = wave_sum(v);
  __syncthreads();
  if ((threadIdx.x & 63) == 0) s[threadIdx.x >> 6] = v;
  __syncthreads();
  return s[0] + s[1] + s[2] + s[3];
}

// ---------------- merged prep: cvt (prev/W_proj only) + all 4 transposes ----
// blocks [0,512): prev cvt, 8 f32/thread; block 0 zeroes rowsum
// blocks [512,896): W_proj cvt, 8 f32/thread
// blocks [896,7808): 32x32 transpose tiles (Wu, Wr, Wn, Wp -> bf16 T)
// NOTE: tokens are NOT converted here anymore - consumers read f32 directly.
__global__ __launch_bounds__(256) void k_prep(
    const float* __restrict__ prev, unsigned short* __restrict__ psb,
    const float* __restrict__ wp, unsigned short* __restrict__ wpb,
    const float* __restrict__ Wu, const float* __restrict__ Wr,
    const float* __restrict__ Wn,
    unsigned short* __restrict__ Wtur, unsigned short* __restrict__ Wtn,
    unsigned short* __restrict__ Wtp, float* __restrict__ rs) {
  __shared__ float tile[32][33];
  const int bid = blockIdx.x;
  if (bid < 896) {
    if (bid == 0) {
      floatx4 z = {0.f, 0.f, 0.f, 0.f};
      *(floatx4*)(rs + threadIdx.x * 4) = z;
    }
    const float* src;
    unsigned short* dst;
    long i;
    if (bid < 512) { src = prev; dst = psb; i = ((long)bid * 256 + threadIdx.x) * 8; }
    else { src = wp; dst = wpb; i = ((long)(bid - 512) * 256 + threadIdx.x) * 8; }
    floatx4 v0 = *(const floatx4*)(src + i);
    floatx4 v1 = *(const floatx4*)(src + i + 4);
    unsigned short t8[8];
#pragma unroll
    for (int j = 0; j < 4; j++) { t8[j] = f2b(v0[j]); t8[4 + j] = f2b(v1[j]); }
    *(uint4*)(dst + i) = *(uint4*)t8;
    return;
  }
  // transpose part
  int t = bid - 896;
  const float* in;
  unsigned short* out;
  int K, kx, ny;
  if (t < 6144) {  // 3 gate weights: each 64 x-blocks * 32 y-blocks
    const int which = t >> 11;
    const int t2 = t & 2047;
    kx = t2 & 63;
    ny = t2 >> 6;
    K = 2048;
    in = which == 0 ? Wu : (which == 1 ? Wr : Wn);
    out = which == 0 ? Wtur : (which == 1 ? Wtur + 1024 * 2048 : Wtn);
  } else {  // W_proj: 24 x-blocks * 32 y-blocks
    const int t2 = t - 6144;
    kx = t2 % 24;
    ny = t2 / 24;
    K = 768;
    in = wp;
    out = Wtp;
  }
  const int N = 1024;
  const int k0 = kx * 32, n0 = ny * 32;
  const int tx = threadIdx.x & 31, ty = threadIdx.x >> 5;
#pragma unroll
  for (int i = 0; i < 32; i += 8)
    tile[ty + i][tx] = in[(long)(k0 + ty + i) * N + n0 + tx];
  __syncthreads();
#pragma unroll
  for (int i = 0; i < 32; i += 8)
    out[(long)(n0 + ty + i) * K + k0 + tx] = f2b(tile[tx][ty + i]);
}

// ---------------- 64x64 MFMA GEMM, BK=64, double-buffered, XCD-swizzled -----
// C[m][n] = A[m][k] * Bt[n][k]  (single matrix, no batch)
// modes: 1: out2 bf16 = v
//        3: out f32  = (1-u)*prev + u*tanh(v+bias)
//        5: c<1024: out f32 = sigmoid(v+bias); else out2 bf16 = sigmoid(v+bias2)*psn
//        6: out f32 = v + aux_u[row]*bias2[c]
__global__ __launch_bounds__(256) void k_gemm64(
    const unsigned short* __restrict__ A, int lda,
    const unsigned short* __restrict__ Bt, int ldb,
    int K,
    const float* __restrict__ bias, const float* __restrict__ bias2,
    int mode,
    void* __restrict__ out, int ldc,
    unsigned short* __restrict__ out2,
    const unsigned short* __restrict__ aux_psn,
    const float* __restrict__ aux_u, const float* __restrict__ aux_prev) {
  __shared__ unsigned short As[2][64 * 64];
  __shared__ unsigned short Bs[2][64 * 64];
  const int tid = threadIdx.x;
  const int wave = tid >> 6, lane = tid & 63;
  // XCD-aware bijective work remap (grid x*y % 8 == 0)
  const int flat = blockIdx.x + blockIdx.y * gridDim.x;
  const int q = (gridDim.x * gridDim.y) >> 3;
  const int swz = (flat & 7) * q + (flat >> 3);
  const int m0 = (swz % gridDim.x) * 64;
  const int n0 = (swz / gridDim.x) * 64;
  const int wm = wave & 1, wn = wave >> 1;
  const int l16 = lane & 15, quad = lane >> 4;
  const int srow8 = lane >> 3;
  const int c8 = ((lane & 7) ^ srow8) * 8;

  const unsigned short* gA[2];
  const unsigned short* gB[2];
  int lOff[2];
#pragma unroll
  for (int j = 0; j < 2; j++) {
    const int rb = wave * 16 + j * 8;
    gA[j] = A + (long)(m0 + rb + srow8) * lda + c8;
    gB[j] = Bt + (long)(n0 + rb + srow8) * ldb + c8;
    lOff[j] = rb * 64;
  }
  int offA[2][2], offB[2][2];
#pragma unroll
  for (int ks = 0; ks < 2; ks++)
#pragma unroll
    for (int i = 0; i < 2; i++) {
      int r = wm * 32 + i * 16 + l16;
      offA[ks][i] = r * 64 + (((ks * 4 + quad) ^ (r & 7)) * 8);
      r = wn * 32 + i * 16 + l16;
      offB[ks][i] = r * 64 + (((ks * 4 + quad) ^ (r & 7)) * 8);
    }

  floatx4 acc[2][2] = {};

#pragma unroll
  for (int j = 0; j < 2; j++) {
    g2l16(gA[j], &As[0][lOff[j]]);
    g2l16(gB[j], &Bs[0][lOff[j]]);
  }
  __syncthreads();

  const int nt = K >> 6;
  for (int t = 0; t < nt; t++) {
    const int cur = t & 1;
    if (t + 1 < nt) {
      const int kn = (t + 1) << 6;
#pragma unroll
      for (int j = 0; j < 2; j++) {
        g2l16(gA[j] + kn, &As[cur ^ 1][lOff[j]]);
        g2l16(gB[j] + kn, &Bs[cur ^ 1][lOff[j]]);
      }
    }
#pragma unroll
    for (int ks = 0; ks < 2; ks++) {
      shortx8 af[2], bf[2];
#pragma unroll
      for (int i = 0; i < 2; i++) af[i] = *(const shortx8*)&As[cur][offA[ks][i]];
#pragma unroll
      for (int j = 0; j < 2; j++) bf[j] = *(const shortx8*)&Bs[cur][offB[ks][j]];
#pragma unroll
      for (int i = 0; i < 2; i++)
#pragma unroll
        for (int j = 0; j < 2; j++)
          acc[i][j] = __builtin_amdgcn_mfma_f32_16x16x32_bf16(af[i], bf[j], acc[i][j], 0, 0, 0);
    }
    __syncthreads();
  }

#pragma unroll
  for (int i = 0; i < 2; i++)
#pragma unroll
    for (int j = 0; j < 2; j++) {
      const int rbase = m0 + wm * 32 + i * 16 + quad * 4;
      const int c = n0 + wn * 32 + j * 16 + l16;
      float bval = 0.0f;
      if (bias) bval = (mode == 5 && c >= 1024) ? bias2[c - 1024] : bias[c];
#pragma unroll
      for (int r = 0; r < 4; r++) {
        const int row = rbase + r;
        float v = acc[i][j][r] + bval;
        if (mode == 1) {
          out2[(long)row * ldc + c] = f2b(v);
        } else if (mode == 3) {
          float cand = tanhf(v);
          float u = aux_u[(long)row * 1024 + c];
          float p = aux_prev[(long)row * 1024 + c];
          ((float*)out)[(long)row * ldc + c] = (1.0f - u) * p + u * cand;
        } else if (mode == 6) {
          ((float*)out)[(long)row * ldc + c] = v + aux_u[row] * bias2[c];
        } else {  // mode 5
          if (c < 1024) {
            ((float*)out)[(long)row * 1024 + c] = 1.0f / (1.0f + expf(-v));
          } else {
            const int cc = c - 1024;
            float rr = 1.0f / (1.0f + expf(-v));
            out2[(long)row * 2048 + cc] = f2b(rr * b2f(aux_psn[(long)row * 2048 + cc]));
          }
        }
      }
    }
}

// ---------------- scores: A=pwb bf16 (g2l16), B=tokens f32 (reg-cvt) --------
// attnb[b][m][c] = exp(pw[b][m][:] . tokens[b][c][:] * scale); rs += row sums
// B staging mimics g2l16 layout: pre-swizzled global cols, linear LDS dest.
__global__ __launch_bounds__(256) void k_scores(
    const unsigned short* __restrict__ A, long sAb, int lda,
    const float* __restrict__ toksf,  // [16][2048][768] f32
    int K, float scale,
    unsigned short* __restrict__ out2, int ldc, long sCb,
    float* __restrict__ rs) {
  __shared__ unsigned short As[2][64 * 64];
  __shared__ unsigned short Bs[2][64 * 64];
  const int tid = threadIdx.x;
  const int wave = tid >> 6, lane = tid & 63;
  const int b = blockIdx.z;
  const int m0 = 0, n0 = blockIdx.y * 64;
  const int wm = wave & 1, wn = wave >> 1;
  const int l16 = lane & 15, quad = lane >> 4;
  const int srow8 = lane >> 3;
  const int c8 = ((lane & 7) ^ srow8) * 8;
  const unsigned short* Ab = A + (long)b * sAb;

  const unsigned short* gA[2];
  const float* gBf[2];
  int lOff[2];
#pragma unroll
  for (int j = 0; j < 2; j++) {
    const int rb = wave * 16 + j * 8;
    gA[j] = Ab + (long)(m0 + rb + srow8) * lda + c8;
    gBf[j] = toksf + (long)b * 1572864 + (long)(n0 + rb + srow8) * 768 + c8;
    lOff[j] = rb * 64;
  }
  int offA[2][2], offB[2][2];
#pragma unroll
  for (int ks = 0; ks < 2; ks++)
#pragma unroll
    for (int i = 0; i < 2; i++) {
      int r = wm * 32 + i * 16 + l16;
      offA[ks][i] = r * 64 + (((ks * 4 + quad) ^ (r & 7)) * 8);
      r = wn * 32 + i * 16 + l16;
      offB[ks][i] = r * 64 + (((ks * 4 + quad) ^ (r & 7)) * 8);
    }

  floatx4 acc[2][2] = {};

  // prologue: stage tile 0
#pragma unroll
  for (int j = 0; j < 2; j++) {
    g2l16(gA[j], &As[0][lOff[j]]);
    floatx4 v0 = *(const floatx4*)(gBf[j]);
    floatx4 v1 = *(const floatx4*)(gBf[j] + 4);
    unsigned short t8[8];
#pragma unroll
    for (int i = 0; i < 4; i++) { t8[i] = f2b(v0[i]); t8[4 + i] = f2b(v1[i]); }
    *(uint4*)&Bs[0][lOff[j] + lane * 8] = *(uint4*)t8;
  }
  __syncthreads();

  const int nt = K >> 6;
  for (int t = 0; t < nt; t++) {
    const int cur = t & 1;
    floatx4 w0[2], w1[2];
    if (t + 1 < nt) {
      const int kn = (t + 1) << 6;
#pragma unroll
      for (int j = 0; j < 2; j++) {
        g2l16(gA[j] + kn, &As[cur ^ 1][lOff[j]]);
        w0[j] = *(const floatx4*)(gBf[j] + kn);
        w1[j] = *(const floatx4*)(gBf[j] + kn + 4);
      }
    }
#pragma unroll
    for (int ks = 0; ks < 2; ks++) {
      shortx8 af[2], bf[2];
#pragma unroll
      for (int i = 0; i < 2; i++) af[i] = *(const shortx8*)&As[cur][offA[ks][i]];
#pragma unroll
      for (int j = 0; j < 2; j++) bf[j] = *(const shortx8*)&Bs[cur][offB[ks][j]];
#pragma unroll
      for (int i = 0; i < 2; i++)
#pragma unroll
        for (int j = 0; j < 2; j++)
          acc[i][j] = __builtin_amdgcn_mfma_f32_16x16x32_bf16(af[i], bf[j], acc[i][j], 0, 0, 0);
    }
    if (t + 1 < nt) {
      // cvt + LDS write after MFMA: global-load latency hidden under compute
#pragma unroll
      for (int j = 0; j < 2; j++) {
        unsigned short t8[8];
#pragma unroll
        for (int i = 0; i < 4; i++) { t8[i] = f2b(w0[j][i]); t8[4 + i] = f2b(w1[j][i]); }
        *(uint4*)&Bs[cur ^ 1][lOff[j] + lane * 8] = *(uint4*)t8;
      }
    }
    __syncthreads();
  }

#pragma unroll
  for (int i = 0; i < 2; i++) {
    float psum[4] = {0.f, 0.f, 0.f, 0.f};
#pragma unroll
    for (int j = 0; j < 2; j++) {
      const int rbase = m0 + wm * 32 + i * 16 + quad * 4;
      const int c = n0 + wn * 32 + j * 16 + l16;
#pragma unroll
      for (int r = 0; r < 4; r++) {
        const float e = expf(acc[i][j][r] * scale);
        out2[(long)b * sCb + (long)(rbase + r) * ldc + c] = f2b(e);
        psum[r] += e;
      }
    }
#pragma unroll
    for (int r = 0; r < 4; r++) {
      float s = psum[r];
      s += __shfl_xor(s, 1, 64);
      s += __shfl_xor(s, 2, 64);
      s += __shfl_xor(s, 4, 64);
      s += __shfl_xor(s, 8, 64);
      if (l16 == 0)
        atomicAdd(rs + (long)b * 64 + m0 + wm * 32 + i * 16 + quad * 4 + r, s);
    }
  }
}

// ---------------- rw = attnb(exp) @ tokens(f32) via MFMA, K-split x2 --------
// attnb [16][64][2048] bf16, toksf [16][2048][768] f32 -> parts [2][1024][768] f32
__global__ __launch_bounds__(256) void k_routed_mfma(
    const unsigned short* __restrict__ attnb,
    const float* __restrict__ tokf,
    float* __restrict__ parts) {
  __shared__ unsigned short As[64 * 40];
  __shared__ unsigned short Bs[32 * 66];
  const int kc = blockIdx.x, nt = blockIdx.y, b = blockIdx.z;
  const int tid = threadIdx.x;
  const int wave = tid >> 6, lane = tid & 63;
  const int wm = wave & 1, wn = wave >> 1;
  const int l16 = lane & 15, quad = lane >> 4;
  const int n0 = nt * 64;
  const long abase = (long)b * 131072 + (long)kc * 1024;
  const long tbase = ((long)b * 2048 + (long)kc * 1024) * 768;
  const int srow = tid >> 2, skc = (tid & 3) * 8;
  const int bk = tid >> 3, bd = (tid & 7) * 8;

  floatx4 acc[2][2] = {};

  // prefetch tile 0 into registers
  uint4 pa = *(const uint4*)(attnb + abase + (long)srow * 2048 + skc);
  floatx4 f0 = *(const floatx4*)(tokf + tbase + (long)bk * 768 + n0 + bd);
  floatx4 f1 = *(const floatx4*)(tokf + tbase + (long)bk * 768 + n0 + bd + 4);

  for (int k0 = 0; k0 < 1024; k0 += 32) {
    // write staged regs to LDS (compiler inserts the vmcnt wait here)
    *(uint4*)&As[srow * 40 + skc] = pa;
    {
      unsigned short t8[8];
#pragma unroll
      for (int i = 0; i < 4; i++) { t8[i] = f2b(f0[i]); t8[4 + i] = f2b(f1[i]); }
      unsigned short* dst = &Bs[bk * 66 + bd];
#pragma unroll
      for (int w2 = 0; w2 < 4; w2++) *(unsigned*)(dst + w2 * 2) = ((unsigned*)t8)[w2];
    }
    // issue next-tile loads; they stay in flight across the barriers below
    if (k0 + 32 < 1024) {
      pa = *(const uint4*)(attnb + abase + (long)srow * 2048 + (k0 + 32) + skc);
      f0 = *(const floatx4*)(tokf + tbase + (long)(k0 + 32 + bk) * 768 + n0 + bd);
      f1 = *(const floatx4*)(tokf + tbase + (long)(k0 + 32 + bk) * 768 + n0 + bd + 4);
    }
    asm volatile("s_waitcnt lgkmcnt(0)" ::: "memory");
    __builtin_amdgcn_s_barrier();
    __builtin_amdgcn_sched_barrier(0);

    shortx8 a0 = *(const shortx8*)&As[(wm * 32 + 0  + l16) * 40 + quad * 8];
    shortx8 a1 = *(const shortx8*)&As[(wm * 32 + 16 + l16) * 40 + quad * 8];
    shortx8 b0, b1;
#pragma unroll
    for (int j = 0; j < 8; j++) {
      b0[j] = *(const short*)&Bs[(quad * 8 + j) * 66 + wn * 32 + l16];
      b1[j] = *(const short*)&Bs[(quad * 8 + j) * 66 + wn * 32 + 16 + l16];
    }
    acc[0][0] = __builtin_amdgcn_mfma_f32_16x16x32_bf16(a0, b0, acc[0][0], 0, 0, 0);
    acc[0][1] = __builtin_amdgcn_mfma_f32_16x16x32_bf16(a0, b1, acc[0][1], 0, 0, 0);
    acc[1][0] = __builtin_amdgcn_mfma_f32_16x16x32_bf16(a1, b0, acc[1][0], 0, 0, 0);
    acc[1][1] = __builtin_amdgcn_mfma_f32_16x16x32_bf16(a1, b1, acc[1][1], 0, 0, 0);
    __builtin_amdgcn_s_barrier();  // all waves done reading LDS before overwrite
  }

#pragma unroll
  for (int im = 0; im < 2; im++)
#pragma unroll
    for (int in_ = 0; in_ < 2; in_++) {
      const int rbase = wm * 32 + im * 16 + quad * 4;
      const int c = n0 + wn * 32 + in_ * 16 + l16;
#pragma unroll
      for (int r = 0; r < 4; r++)
        parts[(long)kc * 786432 + ((long)b * 64 + rbase + r) * 768 + c] =
            acc[im][in_][r];
    }
}

// ---------------- sum the 2 k-split parts, convert to bf16 ------------------
__global__ __launch_bounds__(256) void k_sumcvt(
    const float* __restrict__ parts, unsigned short* __restrict__ out) {
  const long i = ((long)blockIdx.x * 256 + threadIdx.x) * 4;
  floatx4 v = *(const floatx4*)(parts + i);
  floatx4 w = *(const floatx4*)(parts + 786432 + i);
  unsigned short t4[4];
#pragma unroll
  for (int j = 0; j < 4; j++) t4[j] = f2b(v[j] + w[j]);
  *(uint2*)(out + i) = *(uint2*)t4;
}

// ---------------- merged LayerNorms: prev->conc[:, :D], routed->conc/candA --
__global__ __launch_bounds__(256) void k_ln2(
    const float* __restrict__ prev, const float* __restrict__ routed,
    const float* __restrict__ g_st, const float* __restrict__ be_st,
    const float* __restrict__ g_in, const float* __restrict__ be_in,
    unsigned short* __restrict__ conc, unsigned short* __restrict__ candA) {
  __shared__ float scr[4];
  const long r = blockIdx.x & 1023;
  const bool second = blockIdx.x >= 1024;
  const int t = threadIdx.x;
  floatx4 v;
  const float *g, *be;
  if (!second) {
    v = *(const floatx4*)(prev + r * 1024 + t * 4);
    g = g_st; be = be_st;
  } else {
    v = *(const floatx4*)(routed + r * 1024 + t * 4);
    g = g_in; be = be_in;
  }
  float s1 = v[0] + v[1] + v[2] + v[3];
  float s2 = v[0] * v[0] + v[1] * v[1] + v[2] * v[2] + v[3] * v[3];
  s1 = block_sum(s1, scr);
  s2 = block_sum(s2, scr);
  const float mean = s1 * (1.0f / 1024.0f);
  const float var = s2 * (1.0f / 1024.0f) - mean * mean;
  const float rstd = rsqrtf(var + LN_EPS);
#pragma unroll
  for (int i = 0; i < 4; i++) {
    const int d = t * 4 + i;
    const float y = (v[i] - mean) * rstd * g[d] + be[d];
    const unsigned short h = f2b(y);
    if (!second) {
      conc[r * 2048 + d] = h;
    } else {
      conc[r * 2048 + 1024 + d] = h;
      candA[r * 2048 + 1024 + d] = h;
    }
  }
}

// ---------------- final LayerNorm -> f32 output ------------------------------
__global__ __launch_bounds__(256) void k_ln_out(
    const float* __restrict__ in, const float* __restrict__ g,
    const float* __restrict__ be, float* __restrict__ out) {
  __shared__ float scr[4];
  const long r = blockIdx.x;
  const int t = threadIdx.x;
  floatx4 v = *(const floatx4*)(in + r * 1024 + t * 4);
  float s1 = v[0] + v[1] + v[2] + v[3];
  float s2 = v[0] * v[0] + v[1] * v[1] + v[2] * v[2] + v[3] * v[3];
  s1 = block_sum(s1, scr);
  s2 = block_sum(s2, scr);
  const float mean = s1 * (1.0f / 1024.0f);
  const float var = s2 * (1.0f / 1024.0f) - mean * mean;
  const float rstd = rsqrtf(var + LN_EPS);
  floatx4 o;
#pragma unroll
  for (int i = 0; i < 4; i++) {
    const int d = t * 4 + i;
    o[i] = (v[i] - mean) * rstd * g[d] + be[d];
  }
  *(floatx4*)(out + r * 1024 + t * 4) = o;
}

// ---------------------------------------------------------------------------
extern "C" void kernel_launch(void* const* d_in, const int* in_sizes, int n_in,
                              void* d_out, int out_size, void* d_ws, size_t ws_size,
                              hipStream_t stream) {
  (void)in_sizes; (void)n_in; (void)out_size; (void)ws_size;
  const float* prev  = (const float*)d_in[0];
  const float* toks  = (const float*)d_in[1];
  const float* Wp    = (const float*)d_in[2];
  const float* bp    = (const float*)d_in[3];
  const float* g_st  = (const float*)d_in[4];
  const float* be_st = (const float*)d_in[5];
  const float* g_in  = (const float*)d_in[6];
  const float* be_in = (const float*)d_in[7];
  const float* g_o   = (const float*)d_in[8];
  const float* be_o  = (const float*)d_in[9];
  const float* Wu    = (const float*)d_in[10];
  const float* bu    = (const float*)d_in[11];
  const float* Wr    = (const float*)d_in[12];
  const float* br    = (const float*)d_in[13];
  const float* Wn    = (const float*)d_in[14];
  const float* bn    = (const float*)d_in[15];
  float* out = (float*)d_out;

  // ---- workspace (~48 MB) - tokens no longer converted
  char* ws = (char*)d_ws;
  unsigned short* psb   = (unsigned short*)ws; ws += 2097152;   // 1024x1024 bf16
  unsigned short* Wpb   = (unsigned short*)ws; ws += 1572864;   // 768x1024 bf16
  unsigned short* Wtp   = (unsigned short*)ws; ws += 1572864;   // 1024x768 bf16
  unsigned short* pwb   = (unsigned short*)ws; ws += 1572864;   // 1024x768 bf16
  unsigned short* attnb = (unsigned short*)ws; ws += 4194304;   // 16x64x2048 bf16
  float*          rowsum= (float*)ws;          ws += 4096;      // 1024 f32
  float*          parts = (float*)ws;          ws += 6291456;   // 2x 1024x768 f32
  unsigned short* rwb   = (unsigned short*)ws; ws += 1572864;   // 1024x768 bf16
  float*          routed= (float*)ws;          ws += 4194304;   // 1024x1024 f32
  unsigned short* conc  = (unsigned short*)ws; ws += 4194304;   // 1024x2048 bf16
  unsigned short* candA = (unsigned short*)ws; ws += 4194304;   // 1024x2048 bf16
  float*          ubuf  = (float*)ws;          ws += 4194304;   // 1024x1024 f32
  float*          ns    = (float*)ws;          ws += 4194304;   // 1024x1024 f32
  unsigned short* Wtur  = (unsigned short*)ws; ws += 8388608;   // 2048x2048 bf16
  unsigned short* Wtn   = (unsigned short*)ws; ws += 4194304;   // 1024x2048 bf16

  const dim3 blk(256);

  // 1. prep: prev+W_proj cvt, 4 transposes, rowsum zero (no toks pass!)
  k_prep<<<dim3(7808), blk, 0, stream>>>(prev, psb, Wp, Wpb,
                                         Wu, Wr, Wn, Wtur, Wtn, Wtp, rowsum);
  // 2. pw = prev @ W_proj^T  (M=1024, N=768, K=1024) -> bf16 (mode 1), 192 blocks
  k_gemm64<<<dim3(16, 12), blk, 0, stream>>>(
      psb, 1024, Wpb, 1024, 1024,
      nullptr, nullptr, 1,
      nullptr, 768, pwb, nullptr, nullptr, nullptr);
  // 3. attnb = exp(pw @ tokens^T / 32) + fused rowsum atomics, 512 blocks
  //    B operand reads f32 tokens directly, converts during staging.
  k_scores<<<dim3(1, 32, 16), blk, 0, stream>>>(
      pwb, 49152L, 768, toks, 768, 0.03125f,
      attnb, 2048, 131072L, rowsum);
  // 4. rw partials = w @ tokens(f32), K-split x2, 384 blocks
  k_routed_mfma<<<dim3(2, 12, 16), blk, 0, stream>>>(attnb, toks, parts);
  // 5. sum parts -> rwb bf16
  k_sumcvt<<<dim3(768), blk, 0, stream>>>(parts, rwb);
  // 6. routed = rw @ W_proj + rowsum*b_proj  (M=1024, N=1024, K=768, mode 6)
  k_gemm64<<<dim3(16, 16), blk, 0, stream>>>(
      rwb, 768, Wtp, 768, 768,
      nullptr, bp, 6,
      (void*)routed, 1024, nullptr, nullptr, rowsum, nullptr);
  // 7. both LayerNorms
  k_ln2<<<dim3(2048), blk, 0, stream>>>(prev, routed, g_st, be_st, g_in, be_in,
                                        conc, candA);
  // 8. merged u|r gates (mode 5), 512 blocks
  k_gemm64<<<dim3(16, 32), blk, 0, stream>>>(
      conc, 2048, Wtur, 2048, 2048,
      bu, br, 5,
      (void*)ubuf, 1024, candA, conc, nullptr, nullptr);
  // 9. new_state (mode 3), 256 blocks
  k_gemm64<<<dim3(16, 16), blk, 0, stream>>>(
      candA, 2048, Wtn, 2048, 2048,
      bn, nullptr, 3,
      (void*)ns, 1024, nullptr, nullptr, ubuf, prev);
  // 10. final LN -> output
  k_ln_out<<<dim3(1024), blk, 0, stream>>>(ns, g_o, be_o, out);
}

// Round 6
// 305.506 us; speedup vs baseline: 1.4152x; 1.0547x over previous
//
#include <hip/hip_runtime.h>
#include <stdint.h>

typedef __attribute__((ext_vector_type(4))) float floatx4;
typedef __attribute__((ext_vector_type(8))) short shortx8;

#define LN_EPS 1e-5f

__device__ __forceinline__ unsigned short f2b(float f) {
  unsigned u = __builtin_bit_cast(unsigned, f);
  u = (u + 0x7FFFu + ((u >> 16) & 1u)) >> 16;
  return (unsigned short)u;
}
__device__ __forceinline__ float b2f(unsigned short h) {
  return __builtin_bit_cast(float, (unsigned)h << 16);
}

// async global->LDS 16B: lds dest is wave-uniform base; lane i lands at base + i*16
__device__ __forceinline__ void g2l16(const unsigned short* g, unsigned short* l) {
  __builtin_amdgcn_global_load_lds(
      (const __attribute__((address_space(1))) unsigned int*)g,
      (__attribute__((address_space(3))) unsigned int*)l, 16, 0, 0);
}

// ---------------- block reduction helpers (256 threads = 4 waves) -----------
__device__ __forceinline__ float wave_sum(float v) {
#pragma unroll
  for (int o = 32; o; o >>= 1) v += __shfl_down(v, o, 64);
  return v;
}
__device__ __forceinline__ float block_sum(float v, float* s) {
  v = wave_sum(v);
  __syncthreads();
  if ((threadIdx.x & 63) == 0) s[threadIdx.x >> 6] = v;
  __syncthreads();
  return s[0] + s[1] + s[2] + s[3];
}

// ---------------- merged prep: cvt (prev/W_proj only) + all 4 transposes ----
__global__ __launch_bounds__(256) void k_prep(
    const float* __restrict__ prev, unsigned short* __restrict__ psb,
    const float* __restrict__ wp, unsigned short* __restrict__ wpb,
    const float* __restrict__ Wu, const float* __restrict__ Wr,
    const float* __restrict__ Wn,
    unsigned short* __restrict__ Wtur, unsigned short* __restrict__ Wtn,
    unsigned short* __restrict__ Wtp, float* __restrict__ rs) {
  __shared__ float tile[32][33];
  const int bid = blockIdx.x;
  if (bid < 896) {
    if (bid == 0) {
      floatx4 z = {0.f, 0.f, 0.f, 0.f};
      *(floatx4*)(rs + threadIdx.x * 4) = z;
    }
    const float* src;
    unsigned short* dst;
    long i;
    if (bid < 512) { src = prev; dst = psb; i = ((long)bid * 256 + threadIdx.x) * 8; }
    else { src = wp; dst = wpb; i = ((long)(bid - 512) * 256 + threadIdx.x) * 8; }
    floatx4 v0 = *(const floatx4*)(src + i);
    floatx4 v1 = *(const floatx4*)(src + i + 4);
    unsigned short t8[8];
#pragma unroll
    for (int j = 0; j < 4; j++) { t8[j] = f2b(v0[j]); t8[4 + j] = f2b(v1[j]); }
    *(uint4*)(dst + i) = *(uint4*)t8;
    return;
  }
  int t = bid - 896;
  const float* in;
  unsigned short* out;
  int K, kx, ny;
  if (t < 6144) {
    const int which = t >> 11;
    const int t2 = t & 2047;
    kx = t2 & 63;
    ny = t2 >> 6;
    K = 2048;
    in = which == 0 ? Wu : (which == 1 ? Wr : Wn);
    out = which == 0 ? Wtur : (which == 1 ? Wtur + 1024 * 2048 : Wtn);
  } else {
    const int t2 = t - 6144;
    kx = t2 % 24;
    ny = t2 / 24;
    K = 768;
    in = wp;
    out = Wtp;
  }
  const int N = 1024;
  const int k0 = kx * 32, n0 = ny * 32;
  const int tx = threadIdx.x & 31, ty = threadIdx.x >> 5;
#pragma unroll
  for (int i = 0; i < 32; i += 8)
    tile[ty + i][tx] = in[(long)(k0 + ty + i) * N + n0 + tx];
  __syncthreads();
#pragma unroll
  for (int i = 0; i < 32; i += 8)
    out[(long)(n0 + ty + i) * K + k0 + tx] = f2b(tile[tx][ty + i]);
}

// ---------------- 64x64 MFMA GEMM, BK=64, dbuf, XCD-swizzled, K-splittable --
// K = PER-SLICE depth; blockIdx.z = k-slice (1 or 2 slices).
// modes: 1: out2 bf16 = v
//        5: c<1024: out f32 = sigmoid(v+bias); else out2 bf16 = sigmoid(v+bias2)*psn
//        7: out f32 partial = v at [kc*sCk + row*ldc + c]
__global__ __launch_bounds__(256) void k_gemm64(
    const unsigned short* __restrict__ A, int lda,
    const unsigned short* __restrict__ Bt, int ldb,
    int K, long sCk,
    const float* __restrict__ bias, const float* __restrict__ bias2,
    int mode,
    void* __restrict__ out, int ldc,
    unsigned short* __restrict__ out2,
    const unsigned short* __restrict__ aux_psn) {
  __shared__ unsigned short As[2][64 * 64];
  __shared__ unsigned short Bs[2][64 * 64];
  const int tid = threadIdx.x;
  const int wave = tid >> 6, lane = tid & 63;
  const int kc = blockIdx.z;
  const long koff = (long)kc * K;
  // XCD-aware bijective work remap (grid x*y % 8 == 0)
  const int flat = blockIdx.x + blockIdx.y * gridDim.x;
  const int q = (gridDim.x * gridDim.y) >> 3;
  const int swz = (flat & 7) * q + (flat >> 3);
  const int m0 = (swz % gridDim.x) * 64;
  const int n0 = (swz / gridDim.x) * 64;
  const int wm = wave & 1, wn = wave >> 1;
  const int l16 = lane & 15, quad = lane >> 4;
  const int srow8 = lane >> 3;
  const int c8 = ((lane & 7) ^ srow8) * 8;

  const unsigned short* gA[2];
  const unsigned short* gB[2];
  int lOff[2];
#pragma unroll
  for (int j = 0; j < 2; j++) {
    const int rb = wave * 16 + j * 8;
    gA[j] = A + (long)(m0 + rb + srow8) * lda + c8 + koff;
    gB[j] = Bt + (long)(n0 + rb + srow8) * ldb + c8 + koff;
    lOff[j] = rb * 64;
  }
  int offA[2][2], offB[2][2];
#pragma unroll
  for (int ks = 0; ks < 2; ks++)
#pragma unroll
    for (int i = 0; i < 2; i++) {
      int r = wm * 32 + i * 16 + l16;
      offA[ks][i] = r * 64 + (((ks * 4 + quad) ^ (r & 7)) * 8);
      r = wn * 32 + i * 16 + l16;
      offB[ks][i] = r * 64 + (((ks * 4 + quad) ^ (r & 7)) * 8);
    }

  floatx4 acc[2][2] = {};

#pragma unroll
  for (int j = 0; j < 2; j++) {
    g2l16(gA[j], &As[0][lOff[j]]);
    g2l16(gB[j], &Bs[0][lOff[j]]);
  }
  __syncthreads();

  const int nt = K >> 6;
  for (int t = 0; t < nt; t++) {
    const int cur = t & 1;
    if (t + 1 < nt) {
      const int kn = (t + 1) << 6;
#pragma unroll
      for (int j = 0; j < 2; j++) {
        g2l16(gA[j] + kn, &As[cur ^ 1][lOff[j]]);
        g2l16(gB[j] + kn, &Bs[cur ^ 1][lOff[j]]);
      }
    }
#pragma unroll
    for (int ks = 0; ks < 2; ks++) {
      shortx8 af[2], bf[2];
#pragma unroll
      for (int i = 0; i < 2; i++) af[i] = *(const shortx8*)&As[cur][offA[ks][i]];
#pragma unroll
      for (int j = 0; j < 2; j++) bf[j] = *(const shortx8*)&Bs[cur][offB[ks][j]];
#pragma unroll
      for (int i = 0; i < 2; i++)
#pragma unroll
        for (int j = 0; j < 2; j++)
          acc[i][j] = __builtin_amdgcn_mfma_f32_16x16x32_bf16(af[i], bf[j], acc[i][j], 0, 0, 0);
    }
    __syncthreads();
  }

#pragma unroll
  for (int i = 0; i < 2; i++)
#pragma unroll
    for (int j = 0; j < 2; j++) {
      const int rbase = m0 + wm * 32 + i * 16 + quad * 4;
      const int c = n0 + wn * 32 + j * 16 + l16;
      float bval = 0.0f;
      if (bias) bval = (mode == 5 && c >= 1024) ? bias2[c - 1024] : bias[c];
#pragma unroll
      for (int r = 0; r < 4; r++) {
        const int row = rbase + r;
        float v = acc[i][j][r] + bval;
        if (mode == 1) {
          out2[(long)row * ldc + c] = f2b(v);
        } else if (mode == 7) {
          ((float*)out)[(long)kc * sCk + (long)row * ldc + c] = v;
        } else {  // mode 5
          if (c < 1024) {
            ((float*)out)[(long)row * 1024 + c] = 1.0f / (1.0f + expf(-v));
          } else {
            const int cc = c - 1024;
            float rr = 1.0f / (1.0f + expf(-v));
            out2[(long)row * 2048 + cc] = f2b(rr * b2f(aux_psn[(long)row * 2048 + cc]));
          }
        }
      }
    }
}

// ---------------- proj2: A = sum of 2 f32 parts (reg-cvt), B = Wtp (g2l16) --
// routed[row][c] = (parts0+parts1)[row][:] . Wtp[c][:] + rowsum[row]*bp[c]
__global__ __launch_bounds__(256) void k_gemm64_af32(
    const float* __restrict__ P0, int lda,  // parts; P1 = P0 + 786432
    const unsigned short* __restrict__ Bt, int ldb,
    int K,
    const float* __restrict__ bp, const float* __restrict__ rowsum,
    float* __restrict__ out, int ldc) {
  __shared__ unsigned short As[2][64 * 64];
  __shared__ unsigned short Bs[2][64 * 64];
  const int tid = threadIdx.x;
  const int wave = tid >> 6, lane = tid & 63;
  const int flat = blockIdx.x + blockIdx.y * gridDim.x;
  const int q = (gridDim.x * gridDim.y) >> 3;
  const int swz = (flat & 7) * q + (flat >> 3);
  const int m0 = (swz % gridDim.x) * 64;
  const int n0 = (swz / gridDim.x) * 64;
  const int wm = wave & 1, wn = wave >> 1;
  const int l16 = lane & 15, quad = lane >> 4;
  const int srow8 = lane >> 3;
  const int c8 = ((lane & 7) ^ srow8) * 8;

  const float* gAf[2];
  const unsigned short* gB[2];
  int lOff[2];
#pragma unroll
  for (int j = 0; j < 2; j++) {
    const int rb = wave * 16 + j * 8;
    gAf[j] = P0 + (long)(m0 + rb + srow8) * lda + c8;
    gB[j] = Bt + (long)(n0 + rb + srow8) * ldb + c8;
    lOff[j] = rb * 64;
  }
  int offA[2][2], offB[2][2];
#pragma unroll
  for (int ks = 0; ks < 2; ks++)
#pragma unroll
    for (int i = 0; i < 2; i++) {
      int r = wm * 32 + i * 16 + l16;
      offA[ks][i] = r * 64 + (((ks * 4 + quad) ^ (r & 7)) * 8);
      r = wn * 32 + i * 16 + l16;
      offB[ks][i] = r * 64 + (((ks * 4 + quad) ^ (r & 7)) * 8);
    }

  floatx4 acc[2][2] = {};

  // prologue
#pragma unroll
  for (int j = 0; j < 2; j++) {
    g2l16(gB[j], &Bs[0][lOff[j]]);
    floatx4 a0 = *(const floatx4*)(gAf[j]);
    floatx4 a1 = *(const floatx4*)(gAf[j] + 4);
    floatx4 b0 = *(const floatx4*)(gAf[j] + 786432);
    floatx4 b1 = *(const floatx4*)(gAf[j] + 786432 + 4);
    unsigned short t8[8];
#pragma unroll
    for (int i = 0; i < 4; i++) { t8[i] = f2b(a0[i] + b0[i]); t8[4 + i] = f2b(a1[i] + b1[i]); }
    *(uint4*)&As[0][lOff[j] + lane * 8] = *(uint4*)t8;
  }
  __syncthreads();

  const int nt = K >> 6;
  for (int t = 0; t < nt; t++) {
    const int cur = t & 1;
    floatx4 a0[2], a1[2], p0[2], p1[2];
    if (t + 1 < nt) {
      const int kn = (t + 1) << 6;
#pragma unroll
      for (int j = 0; j < 2; j++) {
        g2l16(gB[j] + kn, &Bs[cur ^ 1][lOff[j]]);
        a0[j] = *(const floatx4*)(gAf[j] + kn);
        a1[j] = *(const floatx4*)(gAf[j] + kn + 4);
        p0[j] = *(const floatx4*)(gAf[j] + kn + 786432);
        p1[j] = *(const floatx4*)(gAf[j] + kn + 786432 + 4);
      }
    }
#pragma unroll
    for (int ks = 0; ks < 2; ks++) {
      shortx8 af[2], bf[2];
#pragma unroll
      for (int i = 0; i < 2; i++) af[i] = *(const shortx8*)&As[cur][offA[ks][i]];
#pragma unroll
      for (int j = 0; j < 2; j++) bf[j] = *(const shortx8*)&Bs[cur][offB[ks][j]];
#pragma unroll
      for (int i = 0; i < 2; i++)
#pragma unroll
        for (int j = 0; j < 2; j++)
          acc[i][j] = __builtin_amdgcn_mfma_f32_16x16x32_bf16(af[i], bf[j], acc[i][j], 0, 0, 0);
    }
    if (t + 1 < nt) {
#pragma unroll
      for (int j = 0; j < 2; j++) {
        unsigned short t8[8];
#pragma unroll
        for (int i = 0; i < 4; i++) {
          t8[i] = f2b(a0[j][i] + p0[j][i]);
          t8[4 + i] = f2b(a1[j][i] + p1[j][i]);
        }
        *(uint4*)&As[cur ^ 1][lOff[j] + lane * 8] = *(uint4*)t8;
      }
    }
    __syncthreads();
  }

#pragma unroll
  for (int i = 0; i < 2; i++)
#pragma unroll
    for (int j = 0; j < 2; j++) {
      const int rbase = m0 + wm * 32 + i * 16 + quad * 4;
      const int c = n0 + wn * 32 + j * 16 + l16;
#pragma unroll
      for (int r = 0; r < 4; r++) {
        const int row = rbase + r;
        out[(long)row * ldc + c] = acc[i][j][r] + rowsum[row] * bp[c];
      }
    }
}

// ---------------- scores: A=pwb bf16 (g2l16), B=tokens f32 (reg-cvt) --------
__global__ __launch_bounds__(256) void k_scores(
    const unsigned short* __restrict__ A, long sAb, int lda,
    const float* __restrict__ toksf,
    int K, float scale,
    unsigned short* __restrict__ out2, int ldc, long sCb,
    float* __restrict__ rs) {
  __shared__ unsigned short As[2][64 * 64];
  __shared__ unsigned short Bs[2][64 * 64];
  const int tid = threadIdx.x;
  const int wave = tid >> 6, lane = tid & 63;
  const int b = blockIdx.z;
  const int m0 = 0, n0 = blockIdx.y * 64;
  const int wm = wave & 1, wn = wave >> 1;
  const int l16 = lane & 15, quad = lane >> 4;
  const int srow8 = lane >> 3;
  const int c8 = ((lane & 7) ^ srow8) * 8;
  const unsigned short* Ab = A + (long)b * sAb;

  const unsigned short* gA[2];
  const float* gBf[2];
  int lOff[2];
#pragma unroll
  for (int j = 0; j < 2; j++) {
    const int rb = wave * 16 + j * 8;
    gA[j] = Ab + (long)(m0 + rb + srow8) * lda + c8;
    gBf[j] = toksf + (long)b * 1572864 + (long)(n0 + rb + srow8) * 768 + c8;
    lOff[j] = rb * 64;
  }
  int offA[2][2], offB[2][2];
#pragma unroll
  for (int ks = 0; ks < 2; ks++)
#pragma unroll
    for (int i = 0; i < 2; i++) {
      int r = wm * 32 + i * 16 + l16;
      offA[ks][i] = r * 64 + (((ks * 4 + quad) ^ (r & 7)) * 8);
      r = wn * 32 + i * 16 + l16;
      offB[ks][i] = r * 64 + (((ks * 4 + quad) ^ (r & 7)) * 8);
    }

  floatx4 acc[2][2] = {};

#pragma unroll
  for (int j = 0; j < 2; j++) {
    g2l16(gA[j], &As[0][lOff[j]]);
    floatx4 v0 = *(const floatx4*)(gBf[j]);
    floatx4 v1 = *(const floatx4*)(gBf[j] + 4);
    unsigned short t8[8];
#pragma unroll
    for (int i = 0; i < 4; i++) { t8[i] = f2b(v0[i]); t8[4 + i] = f2b(v1[i]); }
    *(uint4*)&Bs[0][lOff[j] + lane * 8] = *(uint4*)t8;
  }
  __syncthreads();

  const int nt = K >> 6;
  for (int t = 0; t < nt; t++) {
    const int cur = t & 1;
    floatx4 w0[2], w1[2];
    if (t + 1 < nt) {
      const int kn = (t + 1) << 6;
#pragma unroll
      for (int j = 0; j < 2; j++) {
        g2l16(gA[j] + kn, &As[cur ^ 1][lOff[j]]);
        w0[j] = *(const floatx4*)(gBf[j] + kn);
        w1[j] = *(const floatx4*)(gBf[j] + kn + 4);
      }
    }
#pragma unroll
    for (int ks = 0; ks < 2; ks++) {
      shortx8 af[2], bf[2];
#pragma unroll
      for (int i = 0; i < 2; i++) af[i] = *(const shortx8*)&As[cur][offA[ks][i]];
#pragma unroll
      for (int j = 0; j < 2; j++) bf[j] = *(const shortx8*)&Bs[cur][offB[ks][j]];
#pragma unroll
      for (int i = 0; i < 2; i++)
#pragma unroll
        for (int j = 0; j < 2; j++)
          acc[i][j] = __builtin_amdgcn_mfma_f32_16x16x32_bf16(af[i], bf[j], acc[i][j], 0, 0, 0);
    }
    if (t + 1 < nt) {
#pragma unroll
      for (int j = 0; j < 2; j++) {
        unsigned short t8[8];
#pragma unroll
        for (int i = 0; i < 4; i++) { t8[i] = f2b(w0[j][i]); t8[4 + i] = f2b(w1[j][i]); }
        *(uint4*)&Bs[cur ^ 1][lOff[j] + lane * 8] = *(uint4*)t8;
      }
    }
    __syncthreads();
  }

#pragma unroll
  for (int i = 0; i < 2; i++) {
    float psum[4] = {0.f, 0.f, 0.f, 0.f};
#pragma unroll
    for (int j = 0; j < 2; j++) {
      const int rbase = m0 + wm * 32 + i * 16 + quad * 4;
      const int c = n0 + wn * 32 + j * 16 + l16;
#pragma unroll
      for (int r = 0; r < 4; r++) {
        const float e = expf(acc[i][j][r] * scale);
        out2[(long)b * sCb + (long)(rbase + r) * ldc + c] = f2b(e);
        psum[r] += e;
      }
    }
#pragma unroll
    for (int r = 0; r < 4; r++) {
      float s = psum[r];
      s += __shfl_xor(s, 1, 64);
      s += __shfl_xor(s, 2, 64);
      s += __shfl_xor(s, 4, 64);
      s += __shfl_xor(s, 8, 64);
      if (l16 == 0)
        atomicAdd(rs + (long)b * 64 + m0 + wm * 32 + i * 16 + quad * 4 + r, s);
    }
  }
}

// ---------------- rw = attnb(exp) @ tokens(f32) via MFMA, K-split x2 --------
__global__ __launch_bounds__(256) void k_routed_mfma(
    const unsigned short* __restrict__ attnb,
    const float* __restrict__ tokf,
    float* __restrict__ parts) {
  __shared__ unsigned short As[64 * 40];
  __shared__ unsigned short Bs[32 * 66];
  const int kc = blockIdx.x, nt = blockIdx.y, b = blockIdx.z;
  const int tid = threadIdx.x;
  const int wave = tid >> 6, lane = tid & 63;
  const int wm = wave & 1, wn = wave >> 1;
  const int l16 = lane & 15, quad = lane >> 4;
  const int n0 = nt * 64;
  const long abase = (long)b * 131072 + (long)kc * 1024;
  const long tbase = ((long)b * 2048 + (long)kc * 1024) * 768;
  const int srow = tid >> 2, skc = (tid & 3) * 8;
  const int bk = tid >> 3, bd = (tid & 7) * 8;

  floatx4 acc[2][2] = {};

  uint4 pa = *(const uint4*)(attnb + abase + (long)srow * 2048 + skc);
  floatx4 f0 = *(const floatx4*)(tokf + tbase + (long)bk * 768 + n0 + bd);
  floatx4 f1 = *(const floatx4*)(tokf + tbase + (long)bk * 768 + n0 + bd + 4);

  for (int k0 = 0; k0 < 1024; k0 += 32) {
    *(uint4*)&As[srow * 40 + skc] = pa;
    {
      unsigned short t8[8];
#pragma unroll
      for (int i = 0; i < 4; i++) { t8[i] = f2b(f0[i]); t8[4 + i] = f2b(f1[i]); }
      unsigned short* dst = &Bs[bk * 66 + bd];
#pragma unroll
      for (int w2 = 0; w2 < 4; w2++) *(unsigned*)(dst + w2 * 2) = ((unsigned*)t8)[w2];
    }
    if (k0 + 32 < 1024) {
      pa = *(const uint4*)(attnb + abase + (long)srow * 2048 + (k0 + 32) + skc);
      f0 = *(const floatx4*)(tokf + tbase + (long)(k0 + 32 + bk) * 768 + n0 + bd);
      f1 = *(const floatx4*)(tokf + tbase + (long)(k0 + 32 + bk) * 768 + n0 + bd + 4);
    }
    asm volatile("s_waitcnt lgkmcnt(0)" ::: "memory");
    __builtin_amdgcn_s_barrier();
    __builtin_amdgcn_sched_barrier(0);

    shortx8 a0 = *(const shortx8*)&As[(wm * 32 + 0  + l16) * 40 + quad * 8];
    shortx8 a1 = *(const shortx8*)&As[(wm * 32 + 16 + l16) * 40 + quad * 8];
    shortx8 b0, b1;
#pragma unroll
    for (int j = 0; j < 8; j++) {
      b0[j] = *(const short*)&Bs[(quad * 8 + j) * 66 + wn * 32 + l16];
      b1[j] = *(const short*)&Bs[(quad * 8 + j) * 66 + wn * 32 + 16 + l16];
    }
    acc[0][0] = __builtin_amdgcn_mfma_f32_16x16x32_bf16(a0, b0, acc[0][0], 0, 0, 0);
    acc[0][1] = __builtin_amdgcn_mfma_f32_16x16x32_bf16(a0, b1, acc[0][1], 0, 0, 0);
    acc[1][0] = __builtin_amdgcn_mfma_f32_16x16x32_bf16(a1, b0, acc[1][0], 0, 0, 0);
    acc[1][1] = __builtin_amdgcn_mfma_f32_16x16x32_bf16(a1, b1, acc[1][1], 0, 0, 0);
    __builtin_amdgcn_s_barrier();
  }

#pragma unroll
  for (int im = 0; im < 2; im++)
#pragma unroll
    for (int in_ = 0; in_ < 2; in_++) {
      const int rbase = wm * 32 + im * 16 + quad * 4;
      const int c = n0 + wn * 32 + in_ * 16 + l16;
#pragma unroll
      for (int r = 0; r < 4; r++)
        parts[(long)kc * 786432 + ((long)b * 64 + rbase + r) * 768 + c] =
            acc[im][in_][r];
    }
}

// ---------------- merged LayerNorms: prev->conc[:, :D], routed->conc/candA --
__global__ __launch_bounds__(256) void k_ln2(
    const float* __restrict__ prev, const float* __restrict__ routed,
    const float* __restrict__ g_st, const float* __restrict__ be_st,
    const float* __restrict__ g_in, const float* __restrict__ be_in,
    unsigned short* __restrict__ conc, unsigned short* __restrict__ candA) {
  __shared__ float scr[4];
  const long r = blockIdx.x & 1023;
  const bool second = blockIdx.x >= 1024;
  const int t = threadIdx.x;
  floatx4 v;
  const float *g, *be;
  if (!second) {
    v = *(const floatx4*)(prev + r * 1024 + t * 4);
    g = g_st; be = be_st;
  } else {
    v = *(const floatx4*)(routed + r * 1024 + t * 4);
    g = g_in; be = be_in;
  }
  float s1 = v[0] + v[1] + v[2] + v[3];
  float s2 = v[0] * v[0] + v[1] * v[1] + v[2] * v[2] + v[3] * v[3];
  s1 = block_sum(s1, scr);
  s2 = block_sum(s2, scr);
  const float mean = s1 * (1.0f / 1024.0f);
  const float var = s2 * (1.0f / 1024.0f) - mean * mean;
  const float rstd = rsqrtf(var + LN_EPS);
#pragma unroll
  for (int i = 0; i < 4; i++) {
    const int d = t * 4 + i;
    const float y = (v[i] - mean) * rstd * g[d] + be[d];
    const unsigned short h = f2b(y);
    if (!second) {
      conc[r * 2048 + d] = h;
    } else {
      conc[r * 2048 + 1024 + d] = h;
      candA[r * 2048 + 1024 + d] = h;
    }
  }
}

// ---------------- gates epilogue: sigmoid(p0+p1+bias) -> ubuf / r*psn -------
// block = (row, half): half 0 -> ubuf[row][0:1024]; half 1 -> candA[row][0:1024]
__global__ __launch_bounds__(256) void k_gate_epi(
    const float* __restrict__ gparts,  // [2][1024][2048]
    const float* __restrict__ bu, const float* __restrict__ br,
    const unsigned short* __restrict__ conc,
    float* __restrict__ ubuf, unsigned short* __restrict__ candA) {
  const int row = blockIdx.x >> 1;
  const int half = blockIdx.x & 1;
  const int t = threadIdx.x;
  const long base = (long)row * 2048 + half * 1024 + t * 4;
  floatx4 p0 = *(const floatx4*)(gparts + base);
  floatx4 p1 = *(const floatx4*)(gparts + 2097152 + base);
  const float* bias = half ? br : bu;
  floatx4 bv = *(const floatx4*)(bias + t * 4);
  if (!half) {
    floatx4 o;
#pragma unroll
    for (int i = 0; i < 4; i++)
      o[i] = 1.0f / (1.0f + expf(-(p0[i] + p1[i] + bv[i])));
    *(floatx4*)(ubuf + (long)row * 1024 + t * 4) = o;
  } else {
    unsigned short t4[4];
#pragma unroll
    for (int i = 0; i < 4; i++) {
      float rr = 1.0f / (1.0f + expf(-(p0[i] + p1[i] + bv[i])));
      t4[i] = f2b(rr * b2f(conc[(long)row * 2048 + t * 4 + i]));
    }
    *(uint2*)(candA + (long)row * 2048 + t * 4) = *(uint2*)t4;
  }
}

// ---------------- final: cand-epilogue + LayerNorm -> f32 output ------------
// ns = (1-u)*prev + u*tanh(cp0+cp1+bn); out = LN(ns)
__global__ __launch_bounds__(256) void k_ln_out(
    const float* __restrict__ cparts,  // [2][1024][1024]
    const float* __restrict__ ubuf, const float* __restrict__ prev,
    const float* __restrict__ bn,
    const float* __restrict__ g, const float* __restrict__ be,
    float* __restrict__ out) {
  __shared__ float scr[4];
  const long r = blockIdx.x;
  const int t = threadIdx.x;
  floatx4 p0 = *(const floatx4*)(cparts + r * 1024 + t * 4);
  floatx4 p1 = *(const floatx4*)(cparts + 1048576 + r * 1024 + t * 4);
  floatx4 uu = *(const floatx4*)(ubuf + r * 1024 + t * 4);
  floatx4 pv = *(const floatx4*)(prev + r * 1024 + t * 4);
  floatx4 bv = *(const floatx4*)(bn + t * 4);
  floatx4 v;
#pragma unroll
  for (int i = 0; i < 4; i++) {
    const float cand = tanhf(p0[i] + p1[i] + bv[i]);
    v[i] = (1.0f - uu[i]) * pv[i] + uu[i] * cand;
  }
  float s1 = v[0] + v[1] + v[2] + v[3];
  float s2 = v[0] * v[0] + v[1] * v[1] + v[2] * v[2] + v[3] * v[3];
  s1 = block_sum(s1, scr);
  s2 = block_sum(s2, scr);
  const float mean = s1 * (1.0f / 1024.0f);
  const float var = s2 * (1.0f / 1024.0f) - mean * mean;
  const float rstd = rsqrtf(var + LN_EPS);
  floatx4 o;
#pragma unroll
  for (int i = 0; i < 4; i++) {
    const int d = t * 4 + i;
    o[i] = (v[i] - mean) * rstd * g[d] + be[d];
  }
  *(floatx4*)(out + r * 1024 + t * 4) = o;
}

// ---------------------------------------------------------------------------
extern "C" void kernel_launch(void* const* d_in, const int* in_sizes, int n_in,
                              void* d_out, int out_size, void* d_ws, size_t ws_size,
                              hipStream_t stream) {
  (void)in_sizes; (void)n_in; (void)out_size; (void)ws_size;
  const float* prev  = (const float*)d_in[0];
  const float* toks  = (const float*)d_in[1];
  const float* Wp    = (const float*)d_in[2];
  const float* bp    = (const float*)d_in[3];
  const float* g_st  = (const float*)d_in[4];
  const float* be_st = (const float*)d_in[5];
  const float* g_in  = (const float*)d_in[6];
  const float* be_in = (const float*)d_in[7];
  const float* g_o   = (const float*)d_in[8];
  const float* be_o  = (const float*)d_in[9];
  const float* Wu    = (const float*)d_in[10];
  const float* bu    = (const float*)d_in[11];
  const float* Wr    = (const float*)d_in[12];
  const float* br    = (const float*)d_in[13];
  const float* Wn    = (const float*)d_in[14];
  const float* bn    = (const float*)d_in[15];
  float* out = (float*)d_out;

  // ---- workspace (~73 MB)
  char* ws = (char*)d_ws;
  unsigned short* psb   = (unsigned short*)ws; ws += 2097152;   // 1024x1024 bf16
  unsigned short* Wpb   = (unsigned short*)ws; ws += 1572864;   // 768x1024 bf16
  unsigned short* Wtp   = (unsigned short*)ws; ws += 1572864;   // 1024x768 bf16
  unsigned short* pwb   = (unsigned short*)ws; ws += 1572864;   // 1024x768 bf16
  unsigned short* attnb = (unsigned short*)ws; ws += 4194304;   // 16x64x2048 bf16
  float*          rowsum= (float*)ws;          ws += 4096;      // 1024 f32
  float*          parts = (float*)ws;          ws += 6291456;   // 2x 1024x768 f32
  float*          routed= (float*)ws;          ws += 4194304;   // 1024x1024 f32
  unsigned short* conc  = (unsigned short*)ws; ws += 4194304;   // 1024x2048 bf16
  unsigned short* candA = (unsigned short*)ws; ws += 4194304;   // 1024x2048 bf16
  float*          ubuf  = (float*)ws;          ws += 4194304;   // 1024x1024 f32
  unsigned short* Wtur  = (unsigned short*)ws; ws += 8388608;   // 2048x2048 bf16
  unsigned short* Wtn   = (unsigned short*)ws; ws += 4194304;   // 1024x2048 bf16
  float*          gparts= (float*)ws;          ws += 16777216;  // 2x 1024x2048 f32
  float*          cparts= (float*)ws;          ws += 8388608;   // 2x 1024x1024 f32

  const dim3 blk(256);

  // 1. prep: prev+W_proj cvt, 4 transposes, rowsum zero
  k_prep<<<dim3(7808), blk, 0, stream>>>(prev, psb, Wp, Wpb,
                                         Wu, Wr, Wn, Wtur, Wtn, Wtp, rowsum);
  // 2. pw = prev @ W_proj^T -> bf16 (mode 1), 192 blocks
  k_gemm64<<<dim3(16, 12, 1), blk, 0, stream>>>(
      psb, 1024, Wpb, 1024, 1024, 0L,
      nullptr, nullptr, 1,
      nullptr, 768, pwb, nullptr);
  // 3. attnb = exp(pw @ tokens^T / 32) + fused rowsum atomics, 512 blocks
  k_scores<<<dim3(1, 32, 16), blk, 0, stream>>>(
      pwb, 49152L, 768, toks, 768, 0.03125f,
      attnb, 2048, 131072L, rowsum);
  // 4. rw partials = w @ tokens(f32), K-split x2, 384 blocks
  k_routed_mfma<<<dim3(2, 12, 16), blk, 0, stream>>>(attnb, toks, parts);
  // 5. routed = (parts0+parts1) @ W_proj + rowsum*b_proj, 256 blocks
  k_gemm64_af32<<<dim3(16, 16), blk, 0, stream>>>(
      parts, 768, Wtp, 768, 768, bp, rowsum, routed, 1024);
  // 6. both LayerNorms
  k_ln2<<<dim3(2048), blk, 0, stream>>>(prev, routed, g_st, be_st, g_in, be_in,
                                        conc, candA);
  // 7. u|r gates GEMM, K-split x2 (mode 7 partials), 1024 blocks
  k_gemm64<<<dim3(16, 32, 2), blk, 0, stream>>>(
      conc, 2048, Wtur, 2048, 1024, 2097152L,
      nullptr, nullptr, 7,
      (void*)gparts, 2048, nullptr, nullptr);
  // 8. gates epilogue: sigmoid + r*ps_n, 2048 blocks
  k_gate_epi<<<dim3(2048), blk, 0, stream>>>(gparts, bu, br, conc, ubuf, candA);
  // 9. cand GEMM, K-split x2 (mode 7 partials), 512 blocks
  k_gemm64<<<dim3(16, 16, 2), blk, 0, stream>>>(
      candA, 2048, Wtn, 2048, 1024, 1048576L,
      nullptr, nullptr, 7,
      (void*)cparts, 1024, nullptr, nullptr);
  // 10. fused cand-epilogue + final LN -> output
  k_ln_out<<<dim3(1024), blk, 0, stream>>>(cparts, ubuf, prev, bn, g_o, be_o, out);
}

// Round 7
// 294.469 us; speedup vs baseline: 1.4682x; 1.0375x over previous
//
#include <hip/hip_runtime.h>
#include <stdint.h>

typedef __attribute__((ext_vector_type(4))) float floatx4;
typedef __attribute__((ext_vector_type(8))) short shortx8;

#define LN_EPS 1e-5f

__device__ __forceinline__ unsigned short f2b(float f) {
  unsigned u = __builtin_bit_cast(unsigned, f);
  u = (u + 0x7FFFu + ((u >> 16) & 1u)) >> 16;
  return (unsigned short)u;
}
__device__ __forceinline__ float b2f(unsigned short h) {
  return __builtin_bit_cast(float, (unsigned)h << 16);
}

// async global->LDS 16B: lds dest is wave-uniform base; lane i lands at base + i*16
__device__ __forceinline__ void g2l16(const unsigned short* g, unsigned short* l) {
  __builtin_amdgcn_global_load_lds(
      (const __attribute__((address_space(1))) unsigned int*)g,
      (__attribute__((address_space(3))) unsigned int*)l, 16, 0, 0);
}

// ---------------- block reduction helpers (256 threads = 4 waves) -----------
__device__ __forceinline__ float wave_sum(float v) {
#pragma unroll
  for (int o = 32; o; o >>= 1) v += __shfl_down(v, o, 64);
  return v;
}
__device__ __forceinline__ float block_sum(float v, float* s) {
  v = wave_sum(v);
  __syncthreads();
  if ((threadIdx.x & 63) == 0) s[threadIdx.x >> 6] = v;
  __syncthreads();
  return s[0] + s[1] + s[2] + s[3];
}

// ---------------- merged: pw GEMM (blocks 0..191) + transposes + rowsum -----
// pw = prev(f32) @ Wp(f32)^T -> pwb bf16; both operands reg-cvt staged.
// Wp [768][1024] is already the Bt[n][k] layout for this GEMM.
// blocks [192, 7104): 32x32 transpose tiles (Wu,Wr,Wn -> Wtur/Wtn; Wp -> Wtp)
// block 192 additionally zeroes rowsum.
__global__ __launch_bounds__(256) void k_prep_pw(
    const float* __restrict__ prev, const float* __restrict__ wp,
    const float* __restrict__ Wu, const float* __restrict__ Wr,
    const float* __restrict__ Wn,
    unsigned short* __restrict__ Wtur, unsigned short* __restrict__ Wtn,
    unsigned short* __restrict__ Wtp, unsigned short* __restrict__ pwb,
    float* __restrict__ rs) {
  __shared__ unsigned short As[2][64 * 64];
  __shared__ unsigned short Bs[2][64 * 64];
  const int bid = blockIdx.x;
  const int tid = threadIdx.x;
  if (bid < 192) {
    // ---- pw GEMM: M=1024 (16 tiles) x N=768 (12 tiles), K=1024
    const int wave = tid >> 6, lane = tid & 63;
    const int swz = (bid & 7) * 24 + (bid >> 3);  // XCD-bijective over 192
    const int m0 = (swz % 16) * 64;
    const int n0 = (swz / 16) * 64;
    const int wm = wave & 1, wn = wave >> 1;
    const int l16 = lane & 15, quad = lane >> 4;
    const int srow8 = lane >> 3;
    const int c8 = ((lane & 7) ^ srow8) * 8;

    const float* gAf[2];
    const float* gBf[2];
    int lOff[2];
#pragma unroll
    for (int j = 0; j < 2; j++) {
      const int rb = wave * 16 + j * 8;
      gAf[j] = prev + (long)(m0 + rb + srow8) * 1024 + c8;
      gBf[j] = wp + (long)(n0 + rb + srow8) * 1024 + c8;
      lOff[j] = rb * 64;
    }
    int offA[2][2], offB[2][2];
#pragma unroll
    for (int ks = 0; ks < 2; ks++)
#pragma unroll
      for (int i = 0; i < 2; i++) {
        int r = wm * 32 + i * 16 + l16;
        offA[ks][i] = r * 64 + (((ks * 4 + quad) ^ (r & 7)) * 8);
        r = wn * 32 + i * 16 + l16;
        offB[ks][i] = r * 64 + (((ks * 4 + quad) ^ (r & 7)) * 8);
      }

    floatx4 acc[2][2] = {};

    // prologue: stage tile 0 (both operands f32 -> bf16 in regs)
#pragma unroll
    for (int j = 0; j < 2; j++) {
      floatx4 a0 = *(const floatx4*)(gAf[j]);
      floatx4 a1 = *(const floatx4*)(gAf[j] + 4);
      floatx4 b0 = *(const floatx4*)(gBf[j]);
      floatx4 b1 = *(const floatx4*)(gBf[j] + 4);
      unsigned short ta[8], tb[8];
#pragma unroll
      for (int i = 0; i < 4; i++) {
        ta[i] = f2b(a0[i]); ta[4 + i] = f2b(a1[i]);
        tb[i] = f2b(b0[i]); tb[4 + i] = f2b(b1[i]);
      }
      *(uint4*)&As[0][lOff[j] + lane * 8] = *(uint4*)ta;
      *(uint4*)&Bs[0][lOff[j] + lane * 8] = *(uint4*)tb;
    }
    __syncthreads();

    const int nt = 16;
    for (int t = 0; t < nt; t++) {
      const int cur = t & 1;
      floatx4 a0[2], a1[2], b0[2], b1[2];
      if (t + 1 < nt) {
        const int kn = (t + 1) << 6;
#pragma unroll
        for (int j = 0; j < 2; j++) {
          a0[j] = *(const floatx4*)(gAf[j] + kn);
          a1[j] = *(const floatx4*)(gAf[j] + kn + 4);
          b0[j] = *(const floatx4*)(gBf[j] + kn);
          b1[j] = *(const floatx4*)(gBf[j] + kn + 4);
        }
      }
#pragma unroll
      for (int ks = 0; ks < 2; ks++) {
        shortx8 af[2], bf[2];
#pragma unroll
        for (int i = 0; i < 2; i++) af[i] = *(const shortx8*)&As[cur][offA[ks][i]];
#pragma unroll
        for (int j = 0; j < 2; j++) bf[j] = *(const shortx8*)&Bs[cur][offB[ks][j]];
#pragma unroll
        for (int i = 0; i < 2; i++)
#pragma unroll
          for (int j = 0; j < 2; j++)
            acc[i][j] = __builtin_amdgcn_mfma_f32_16x16x32_bf16(af[i], bf[j], acc[i][j], 0, 0, 0);
      }
      if (t + 1 < nt) {
#pragma unroll
        for (int j = 0; j < 2; j++) {
          unsigned short ta[8], tb[8];
#pragma unroll
          for (int i = 0; i < 4; i++) {
            ta[i] = f2b(a0[j][i]); ta[4 + i] = f2b(a1[j][i]);
            tb[i] = f2b(b0[j][i]); tb[4 + i] = f2b(b1[j][i]);
          }
          *(uint4*)&As[cur ^ 1][lOff[j] + lane * 8] = *(uint4*)ta;
          *(uint4*)&Bs[cur ^ 1][lOff[j] + lane * 8] = *(uint4*)tb;
        }
      }
      __syncthreads();
    }

#pragma unroll
    for (int i = 0; i < 2; i++)
#pragma unroll
      for (int j = 0; j < 2; j++) {
        const int rbase = m0 + wm * 32 + i * 16 + quad * 4;
        const int c = n0 + wn * 32 + j * 16 + l16;
#pragma unroll
        for (int r = 0; r < 4; r++)
          pwb[(long)(rbase + r) * 768 + c] = f2b(acc[i][j][r]);
      }
    return;
  }
  // ---- transpose part (aliases LDS)
  float(*tile)[33] = (float(*)[33]) & As[0][0];
  if (bid == 192) {
    floatx4 z = {0.f, 0.f, 0.f, 0.f};
    *(floatx4*)(rs + tid * 4) = z;
  }
  int t = bid - 192;
  const float* in;
  unsigned short* out;
  int K, kx, ny;
  if (t < 6144) {
    const int which = t >> 11;
    const int t2 = t & 2047;
    kx = t2 & 63;
    ny = t2 >> 6;
    K = 2048;
    in = which == 0 ? Wu : (which == 1 ? Wr : Wn);
    out = which == 0 ? Wtur : (which == 1 ? Wtur + 1024 * 2048 : Wtn);
  } else {
    const int t2 = t - 6144;
    kx = t2 % 24;
    ny = t2 / 24;
    K = 768;
    in = wp;
    out = Wtp;
  }
  const int N = 1024;
  const int k0 = kx * 32, n0 = ny * 32;
  const int tx = tid & 31, ty = tid >> 5;
#pragma unroll
  for (int i = 0; i < 32; i += 8)
    tile[ty + i][tx] = in[(long)(k0 + ty + i) * N + n0 + tx];
  __syncthreads();
#pragma unroll
  for (int i = 0; i < 32; i += 8)
    out[(long)(n0 + ty + i) * K + k0 + tx] = f2b(tile[tx][ty + i]);
}

// ---------------- 64x64 MFMA GEMM, BK=64, dbuf, XCD-swizzled, K-splittable --
// K = PER-SLICE depth; blockIdx.z = k-slice. mode 7: f32 partials.
__global__ __launch_bounds__(256) void k_gemm64(
    const unsigned short* __restrict__ A, int lda,
    const unsigned short* __restrict__ Bt, int ldb,
    int K, long sCk,
    float* __restrict__ out, int ldc) {
  __shared__ unsigned short As[2][64 * 64];
  __shared__ unsigned short Bs[2][64 * 64];
  const int tid = threadIdx.x;
  const int wave = tid >> 6, lane = tid & 63;
  const int kc = blockIdx.z;
  const long koff = (long)kc * K;
  const int flat = blockIdx.x + blockIdx.y * gridDim.x;
  const int q = (gridDim.x * gridDim.y) >> 3;
  const int swz = (flat & 7) * q + (flat >> 3);
  const int m0 = (swz % gridDim.x) * 64;
  const int n0 = (swz / gridDim.x) * 64;
  const int wm = wave & 1, wn = wave >> 1;
  const int l16 = lane & 15, quad = lane >> 4;
  const int srow8 = lane >> 3;
  const int c8 = ((lane & 7) ^ srow8) * 8;

  const unsigned short* gA[2];
  const unsigned short* gB[2];
  int lOff[2];
#pragma unroll
  for (int j = 0; j < 2; j++) {
    const int rb = wave * 16 + j * 8;
    gA[j] = A + (long)(m0 + rb + srow8) * lda + c8 + koff;
    gB[j] = Bt + (long)(n0 + rb + srow8) * ldb + c8 + koff;
    lOff[j] = rb * 64;
  }
  int offA[2][2], offB[2][2];
#pragma unroll
  for (int ks = 0; ks < 2; ks++)
#pragma unroll
    for (int i = 0; i < 2; i++) {
      int r = wm * 32 + i * 16 + l16;
      offA[ks][i] = r * 64 + (((ks * 4 + quad) ^ (r & 7)) * 8);
      r = wn * 32 + i * 16 + l16;
      offB[ks][i] = r * 64 + (((ks * 4 + quad) ^ (r & 7)) * 8);
    }

  floatx4 acc[2][2] = {};

#pragma unroll
  for (int j = 0; j < 2; j++) {
    g2l16(gA[j], &As[0][lOff[j]]);
    g2l16(gB[j], &Bs[0][lOff[j]]);
  }
  __syncthreads();

  const int nt = K >> 6;
  for (int t = 0; t < nt; t++) {
    const int cur = t & 1;
    if (t + 1 < nt) {
      const int kn = (t + 1) << 6;
#pragma unroll
      for (int j = 0; j < 2; j++) {
        g2l16(gA[j] + kn, &As[cur ^ 1][lOff[j]]);
        g2l16(gB[j] + kn, &Bs[cur ^ 1][lOff[j]]);
      }
    }
#pragma unroll
    for (int ks = 0; ks < 2; ks++) {
      shortx8 af[2], bf[2];
#pragma unroll
      for (int i = 0; i < 2; i++) af[i] = *(const shortx8*)&As[cur][offA[ks][i]];
#pragma unroll
      for (int j = 0; j < 2; j++) bf[j] = *(const shortx8*)&Bs[cur][offB[ks][j]];
#pragma unroll
      for (int i = 0; i < 2; i++)
#pragma unroll
        for (int j = 0; j < 2; j++)
          acc[i][j] = __builtin_amdgcn_mfma_f32_16x16x32_bf16(af[i], bf[j], acc[i][j], 0, 0, 0);
    }
    __syncthreads();
  }

#pragma unroll
  for (int i = 0; i < 2; i++)
#pragma unroll
    for (int j = 0; j < 2; j++) {
      const int rbase = m0 + wm * 32 + i * 16 + quad * 4;
      const int c = n0 + wn * 32 + j * 16 + l16;
#pragma unroll
      for (int r = 0; r < 4; r++)
        out[(long)kc * sCk + (long)(rbase + r) * ldc + c] = acc[i][j][r];
    }
}

// ---------------- proj2 (blocks 0..255) + prev-LN (blocks 256..1279) --------
// proj2: routed[row][c] = (parts0+parts1)[row][:] . Wtp[c][:] + rowsum[row]*bp[c]
// prevLN: conc[r][0:1024] = LN(prev[r]) * g_st + be_st
__global__ __launch_bounds__(256) void k_proj2_ln(
    const float* __restrict__ P0, int lda,
    const unsigned short* __restrict__ Bt, int ldb,
    int K,
    const float* __restrict__ bp, const float* __restrict__ rowsum,
    float* __restrict__ out, int ldc,
    const float* __restrict__ prev,
    const float* __restrict__ g_st, const float* __restrict__ be_st,
    unsigned short* __restrict__ conc) {
  __shared__ unsigned short As[2][64 * 64];
  __shared__ unsigned short Bs[2][64 * 64];
  const int tid = threadIdx.x;
  if (blockIdx.x >= 256) {
    // ---- prev-LN
    float* scr = (float*)&As[0][0];
    const long r = blockIdx.x - 256;
    floatx4 v = *(const floatx4*)(prev + r * 1024 + tid * 4);
    float s1 = v[0] + v[1] + v[2] + v[3];
    float s2 = v[0] * v[0] + v[1] * v[1] + v[2] * v[2] + v[3] * v[3];
    s1 = block_sum(s1, scr);
    s2 = block_sum(s2, scr);
    const float mean = s1 * (1.0f / 1024.0f);
    const float var = s2 * (1.0f / 1024.0f) - mean * mean;
    const float rstd = rsqrtf(var + LN_EPS);
    unsigned short t4[4];
#pragma unroll
    for (int i = 0; i < 4; i++) {
      const int d = tid * 4 + i;
      t4[i] = f2b((v[i] - mean) * rstd * g_st[d] + be_st[d]);
    }
    *(uint2*)(conc + r * 2048 + tid * 4) = *(uint2*)t4;
    return;
  }
  // ---- proj2
  const int wave = tid >> 6, lane = tid & 63;
  const int flat = blockIdx.x;
  const int swz = (flat & 7) * 32 + (flat >> 3);  // bijective over 256
  const int m0 = (swz % 16) * 64;
  const int n0 = (swz / 16) * 64;
  const int wm = wave & 1, wn = wave >> 1;
  const int l16 = lane & 15, quad = lane >> 4;
  const int srow8 = lane >> 3;
  const int c8 = ((lane & 7) ^ srow8) * 8;

  const float* gAf[2];
  const unsigned short* gB[2];
  int lOff[2];
#pragma unroll
  for (int j = 0; j < 2; j++) {
    const int rb = wave * 16 + j * 8;
    gAf[j] = P0 + (long)(m0 + rb + srow8) * lda + c8;
    gB[j] = Bt + (long)(n0 + rb + srow8) * ldb + c8;
    lOff[j] = rb * 64;
  }
  int offA[2][2], offB[2][2];
#pragma unroll
  for (int ks = 0; ks < 2; ks++)
#pragma unroll
    for (int i = 0; i < 2; i++) {
      int r = wm * 32 + i * 16 + l16;
      offA[ks][i] = r * 64 + (((ks * 4 + quad) ^ (r & 7)) * 8);
      r = wn * 32 + i * 16 + l16;
      offB[ks][i] = r * 64 + (((ks * 4 + quad) ^ (r & 7)) * 8);
    }

  floatx4 acc[2][2] = {};

#pragma unroll
  for (int j = 0; j < 2; j++) {
    g2l16(gB[j], &Bs[0][lOff[j]]);
    floatx4 a0 = *(const floatx4*)(gAf[j]);
    floatx4 a1 = *(const floatx4*)(gAf[j] + 4);
    floatx4 b0 = *(const floatx4*)(gAf[j] + 786432);
    floatx4 b1 = *(const floatx4*)(gAf[j] + 786432 + 4);
    unsigned short t8[8];
#pragma unroll
    for (int i = 0; i < 4; i++) { t8[i] = f2b(a0[i] + b0[i]); t8[4 + i] = f2b(a1[i] + b1[i]); }
    *(uint4*)&As[0][lOff[j] + lane * 8] = *(uint4*)t8;
  }
  __syncthreads();

  const int nt = K >> 6;
  for (int t = 0; t < nt; t++) {
    const int cur = t & 1;
    floatx4 a0[2], a1[2], p0[2], p1[2];
    if (t + 1 < nt) {
      const int kn = (t + 1) << 6;
#pragma unroll
      for (int j = 0; j < 2; j++) {
        g2l16(gB[j] + kn, &Bs[cur ^ 1][lOff[j]]);
        a0[j] = *(const floatx4*)(gAf[j] + kn);
        a1[j] = *(const floatx4*)(gAf[j] + kn + 4);
        p0[j] = *(const floatx4*)(gAf[j] + kn + 786432);
        p1[j] = *(const floatx4*)(gAf[j] + kn + 786432 + 4);
      }
    }
#pragma unroll
    for (int ks = 0; ks < 2; ks++) {
      shortx8 af[2], bf[2];
#pragma unroll
      for (int i = 0; i < 2; i++) af[i] = *(const shortx8*)&As[cur][offA[ks][i]];
#pragma unroll
      for (int j = 0; j < 2; j++) bf[j] = *(const shortx8*)&Bs[cur][offB[ks][j]];
#pragma unroll
      for (int i = 0; i < 2; i++)
#pragma unroll
        for (int j = 0; j < 2; j++)
          acc[i][j] = __builtin_amdgcn_mfma_f32_16x16x32_bf16(af[i], bf[j], acc[i][j], 0, 0, 0);
    }
    if (t + 1 < nt) {
#pragma unroll
      for (int j = 0; j < 2; j++) {
        unsigned short t8[8];
#pragma unroll
        for (int i = 0; i < 4; i++) {
          t8[i] = f2b(a0[j][i] + p0[j][i]);
          t8[4 + i] = f2b(a1[j][i] + p1[j][i]);
        }
        *(uint4*)&As[cur ^ 1][lOff[j] + lane * 8] = *(uint4*)t8;
      }
    }
    __syncthreads();
  }

#pragma unroll
  for (int i = 0; i < 2; i++)
#pragma unroll
    for (int j = 0; j < 2; j++) {
      const int rbase = m0 + wm * 32 + i * 16 + quad * 4;
      const int c = n0 + wn * 32 + j * 16 + l16;
#pragma unroll
      for (int r = 0; r < 4; r++) {
        const int row = rbase + r;
        out[(long)row * ldc + c] = acc[i][j][r] + rowsum[row] * bp[c];
      }
    }
}

// ---------------- scores: A=pwb bf16 (g2l16), B=tokens f32 (reg-cvt) --------
__global__ __launch_bounds__(256) void k_scores(
    const unsigned short* __restrict__ A, long sAb, int lda,
    const float* __restrict__ toksf,
    int K, float scale,
    unsigned short* __restrict__ out2, int ldc, long sCb,
    float* __restrict__ rs) {
  __shared__ unsigned short As[2][64 * 64];
  __shared__ unsigned short Bs[2][64 * 64];
  const int tid = threadIdx.x;
  const int wave = tid >> 6, lane = tid & 63;
  const int b = blockIdx.z;
  const int m0 = 0, n0 = blockIdx.y * 64;
  const int wm = wave & 1, wn = wave >> 1;
  const int l16 = lane & 15, quad = lane >> 4;
  const int srow8 = lane >> 3;
  const int c8 = ((lane & 7) ^ srow8) * 8;
  const unsigned short* Ab = A + (long)b * sAb;

  const unsigned short* gA[2];
  const float* gBf[2];
  int lOff[2];
#pragma unroll
  for (int j = 0; j < 2; j++) {
    const int rb = wave * 16 + j * 8;
    gA[j] = Ab + (long)(m0 + rb + srow8) * lda + c8;
    gBf[j] = toksf + (long)b * 1572864 + (long)(n0 + rb + srow8) * 768 + c8;
    lOff[j] = rb * 64;
  }
  int offA[2][2], offB[2][2];
#pragma unroll
  for (int ks = 0; ks < 2; ks++)
#pragma unroll
    for (int i = 0; i < 2; i++) {
      int r = wm * 32 + i * 16 + l16;
      offA[ks][i] = r * 64 + (((ks * 4 + quad) ^ (r & 7)) * 8);
      r = wn * 32 + i * 16 + l16;
      offB[ks][i] = r * 64 + (((ks * 4 + quad) ^ (r & 7)) * 8);
    }

  floatx4 acc[2][2] = {};

#pragma unroll
  for (int j = 0; j < 2; j++) {
    g2l16(gA[j], &As[0][lOff[j]]);
    floatx4 v0 = *(const floatx4*)(gBf[j]);
    floatx4 v1 = *(const floatx4*)(gBf[j] + 4);
    unsigned short t8[8];
#pragma unroll
    for (int i = 0; i < 4; i++) { t8[i] = f2b(v0[i]); t8[4 + i] = f2b(v1[i]); }
    *(uint4*)&Bs[0][lOff[j] + lane * 8] = *(uint4*)t8;
  }
  __syncthreads();

  const int nt = K >> 6;
  for (int t = 0; t < nt; t++) {
    const int cur = t & 1;
    floatx4 w0[2], w1[2];
    if (t + 1 < nt) {
      const int kn = (t + 1) << 6;
#pragma unroll
      for (int j = 0; j < 2; j++) {
        g2l16(gA[j] + kn, &As[cur ^ 1][lOff[j]]);
        w0[j] = *(const floatx4*)(gBf[j] + kn);
        w1[j] = *(const floatx4*)(gBf[j] + kn + 4);
      }
    }
#pragma unroll
    for (int ks = 0; ks < 2; ks++) {
      shortx8 af[2], bf[2];
#pragma unroll
      for (int i = 0; i < 2; i++) af[i] = *(const shortx8*)&As[cur][offA[ks][i]];
#pragma unroll
      for (int j = 0; j < 2; j++) bf[j] = *(const shortx8*)&Bs[cur][offB[ks][j]];
#pragma unroll
      for (int i = 0; i < 2; i++)
#pragma unroll
        for (int j = 0; j < 2; j++)
          acc[i][j] = __builtin_amdgcn_mfma_f32_16x16x32_bf16(af[i], bf[j], acc[i][j], 0, 0, 0);
    }
    if (t + 1 < nt) {
#pragma unroll
      for (int j = 0; j < 2; j++) {
        unsigned short t8[8];
#pragma unroll
        for (int i = 0; i < 4; i++) { t8[i] = f2b(w0[j][i]); t8[4 + i] = f2b(w1[j][i]); }
        *(uint4*)&Bs[cur ^ 1][lOff[j] + lane * 8] = *(uint4*)t8;
      }
    }
    __syncthreads();
  }

#pragma unroll
  for (int i = 0; i < 2; i++) {
    float psum[4] = {0.f, 0.f, 0.f, 0.f};
#pragma unroll
    for (int j = 0; j < 2; j++) {
      const int rbase = m0 + wm * 32 + i * 16 + quad * 4;
      const int c = n0 + wn * 32 + j * 16 + l16;
#pragma unroll
      for (int r = 0; r < 4; r++) {
        const float e = expf(acc[i][j][r] * scale);
        out2[(long)b * sCb + (long)(rbase + r) * ldc + c] = f2b(e);
        psum[r] += e;
      }
    }
#pragma unroll
    for (int r = 0; r < 4; r++) {
      float s = psum[r];
      s += __shfl_xor(s, 1, 64);
      s += __shfl_xor(s, 2, 64);
      s += __shfl_xor(s, 4, 64);
      s += __shfl_xor(s, 8, 64);
      if (l16 == 0)
        atomicAdd(rs + (long)b * 64 + m0 + wm * 32 + i * 16 + quad * 4 + r, s);
    }
  }
}

// ---------------- rw = attnb(exp) @ tokens(f32) via MFMA, K-split x2 --------
__global__ __launch_bounds__(256) void k_routed_mfma(
    const unsigned short* __restrict__ attnb,
    const float* __restrict__ tokf,
    float* __restrict__ parts) {
  __shared__ unsigned short As[64 * 40];
  __shared__ unsigned short Bs[32 * 66];
  const int kc = blockIdx.x, nt = blockIdx.y, b = blockIdx.z;
  const int tid = threadIdx.x;
  const int wave = tid >> 6, lane = tid & 63;
  const int wm = wave & 1, wn = wave >> 1;
  const int l16 = lane & 15, quad = lane >> 4;
  const int n0 = nt * 64;
  const long abase = (long)b * 131072 + (long)kc * 1024;
  const long tbase = ((long)b * 2048 + (long)kc * 1024) * 768;
  const int srow = tid >> 2, skc = (tid & 3) * 8;
  const int bk = tid >> 3, bd = (tid & 7) * 8;

  floatx4 acc[2][2] = {};

  uint4 pa = *(const uint4*)(attnb + abase + (long)srow * 2048 + skc);
  floatx4 f0 = *(const floatx4*)(tokf + tbase + (long)bk * 768 + n0 + bd);
  floatx4 f1 = *(const floatx4*)(tokf + tbase + (long)bk * 768 + n0 + bd + 4);

  for (int k0 = 0; k0 < 1024; k0 += 32) {
    *(uint4*)&As[srow * 40 + skc] = pa;
    {
      unsigned short t8[8];
#pragma unroll
      for (int i = 0; i < 4; i++) { t8[i] = f2b(f0[i]); t8[4 + i] = f2b(f1[i]); }
      unsigned short* dst = &Bs[bk * 66 + bd];
#pragma unroll
      for (int w2 = 0; w2 < 4; w2++) *(unsigned*)(dst + w2 * 2) = ((unsigned*)t8)[w2];
    }
    if (k0 + 32 < 1024) {
      pa = *(const uint4*)(attnb + abase + (long)srow * 2048 + (k0 + 32) + skc);
      f0 = *(const floatx4*)(tokf + tbase + (long)(k0 + 32 + bk) * 768 + n0 + bd);
      f1 = *(const floatx4*)(tokf + tbase + (long)(k0 + 32 + bk) * 768 + n0 + bd + 4);
    }
    asm volatile("s_waitcnt lgkmcnt(0)" ::: "memory");
    __builtin_amdgcn_s_barrier();
    __builtin_amdgcn_sched_barrier(0);

    shortx8 a0 = *(const shortx8*)&As[(wm * 32 + 0  + l16) * 40 + quad * 8];
    shortx8 a1 = *(const shortx8*)&As[(wm * 32 + 16 + l16) * 40 + quad * 8];
    shortx8 b0, b1;
#pragma unroll
    for (int j = 0; j < 8; j++) {
      b0[j] = *(const short*)&Bs[(quad * 8 + j) * 66 + wn * 32 + l16];
      b1[j] = *(const short*)&Bs[(quad * 8 + j) * 66 + wn * 32 + 16 + l16];
    }
    acc[0][0] = __builtin_amdgcn_mfma_f32_16x16x32_bf16(a0, b0, acc[0][0], 0, 0, 0);
    acc[0][1] = __builtin_amdgcn_mfma_f32_16x16x32_bf16(a0, b1, acc[0][1], 0, 0, 0);
    acc[1][0] = __builtin_amdgcn_mfma_f32_16x16x32_bf16(a1, b0, acc[1][0], 0, 0, 0);
    acc[1][1] = __builtin_amdgcn_mfma_f32_16x16x32_bf16(a1, b1, acc[1][1], 0, 0, 0);
    __builtin_amdgcn_s_barrier();
  }

#pragma unroll
  for (int im = 0; im < 2; im++)
#pragma unroll
    for (int in_ = 0; in_ < 2; in_++) {
      const int rbase = wm * 32 + im * 16 + quad * 4;
      const int c = n0 + wn * 32 + in_ * 16 + l16;
#pragma unroll
      for (int r = 0; r < 4; r++)
        parts[(long)kc * 786432 + ((long)b * 64 + rbase + r) * 768 + c] =
            acc[im][in_][r];
    }
}

// ---------------- routed LayerNorm -> conc second half + candA second half --
__global__ __launch_bounds__(256) void k_ln_routed(
    const float* __restrict__ routed,
    const float* __restrict__ g_in, const float* __restrict__ be_in,
    unsigned short* __restrict__ conc, unsigned short* __restrict__ candA) {
  __shared__ float scr[4];
  const long r = blockIdx.x;
  const int t = threadIdx.x;
  floatx4 v = *(const floatx4*)(routed + r * 1024 + t * 4);
  float s1 = v[0] + v[1] + v[2] + v[3];
  float s2 = v[0] * v[0] + v[1] * v[1] + v[2] * v[2] + v[3] * v[3];
  s1 = block_sum(s1, scr);
  s2 = block_sum(s2, scr);
  const float mean = s1 * (1.0f / 1024.0f);
  const float var = s2 * (1.0f / 1024.0f) - mean * mean;
  const float rstd = rsqrtf(var + LN_EPS);
  unsigned short t4[4];
#pragma unroll
  for (int i = 0; i < 4; i++) {
    const int d = t * 4 + i;
    t4[i] = f2b((v[i] - mean) * rstd * g_in[d] + be_in[d]);
  }
  *(uint2*)(conc + r * 2048 + 1024 + t * 4) = *(uint2*)t4;
  *(uint2*)(candA + r * 2048 + 1024 + t * 4) = *(uint2*)t4;
}

// ---------------- gates epilogue: sigmoid(p0+p1+bias) -> ubuf / r*psn -------
__global__ __launch_bounds__(256) void k_gate_epi(
    const float* __restrict__ gparts,  // [2][1024][2048]
    const float* __restrict__ bu, const float* __restrict__ br,
    const unsigned short* __restrict__ conc,
    float* __restrict__ ubuf, unsigned short* __restrict__ candA) {
  const int row = blockIdx.x >> 1;
  const int half = blockIdx.x & 1;
  const int t = threadIdx.x;
  const long base = (long)row * 2048 + half * 1024 + t * 4;
  floatx4 p0 = *(const floatx4*)(gparts + base);
  floatx4 p1 = *(const floatx4*)(gparts + 2097152 + base);
  const float* bias = half ? br : bu;
  floatx4 bv = *(const floatx4*)(bias + t * 4);
  if (!half) {
    floatx4 o;
#pragma unroll
    for (int i = 0; i < 4; i++)
      o[i] = 1.0f / (1.0f + expf(-(p0[i] + p1[i] + bv[i])));
    *(floatx4*)(ubuf + (long)row * 1024 + t * 4) = o;
  } else {
    unsigned short t4[4];
#pragma unroll
    for (int i = 0; i < 4; i++) {
      float rr = 1.0f / (1.0f + expf(-(p0[i] + p1[i] + bv[i])));
      t4[i] = f2b(rr * b2f(conc[(long)row * 2048 + t * 4 + i]));
    }
    *(uint2*)(candA + (long)row * 2048 + t * 4) = *(uint2*)t4;
  }
}

// ---------------- final: cand-epilogue + LayerNorm -> f32 output ------------
__global__ __launch_bounds__(256) void k_ln_out(
    const float* __restrict__ cparts,  // [2][1024][1024]
    const float* __restrict__ ubuf, const float* __restrict__ prev,
    const float* __restrict__ bn,
    const float* __restrict__ g, const float* __restrict__ be,
    float* __restrict__ out) {
  __shared__ float scr[4];
  const long r = blockIdx.x;
  const int t = threadIdx.x;
  floatx4 p0 = *(const floatx4*)(cparts + r * 1024 + t * 4);
  floatx4 p1 = *(const floatx4*)(cparts + 1048576 + r * 1024 + t * 4);
  floatx4 uu = *(const floatx4*)(ubuf + r * 1024 + t * 4);
  floatx4 pv = *(const floatx4*)(prev + r * 1024 + t * 4);
  floatx4 bv = *(const floatx4*)(bn + t * 4);
  floatx4 v;
#pragma unroll
  for (int i = 0; i < 4; i++) {
    const float cand = tanhf(p0[i] + p1[i] + bv[i]);
    v[i] = (1.0f - uu[i]) * pv[i] + uu[i] * cand;
  }
  float s1 = v[0] + v[1] + v[2] + v[3];
  float s2 = v[0] * v[0] + v[1] * v[1] + v[2] * v[2] + v[3] * v[3];
  s1 = block_sum(s1, scr);
  s2 = block_sum(s2, scr);
  const float mean = s1 * (1.0f / 1024.0f);
  const float var = s2 * (1.0f / 1024.0f) - mean * mean;
  const float rstd = rsqrtf(var + LN_EPS);
  floatx4 o;
#pragma unroll
  for (int i = 0; i < 4; i++) {
    const int d = t * 4 + i;
    o[i] = (v[i] - mean) * rstd * g[d] + be[d];
  }
  *(floatx4*)(out + r * 1024 + t * 4) = o;
}

// ---------------------------------------------------------------------------
extern "C" void kernel_launch(void* const* d_in, const int* in_sizes, int n_in,
                              void* d_out, int out_size, void* d_ws, size_t ws_size,
                              hipStream_t stream) {
  (void)in_sizes; (void)n_in; (void)out_size; (void)ws_size;
  const float* prev  = (const float*)d_in[0];
  const float* toks  = (const float*)d_in[1];
  const float* Wp    = (const float*)d_in[2];
  const float* bp    = (const float*)d_in[3];
  const float* g_st  = (const float*)d_in[4];
  const float* be_st = (const float*)d_in[5];
  const float* g_in  = (const float*)d_in[6];
  const float* be_in = (const float*)d_in[7];
  const float* g_o   = (const float*)d_in[8];
  const float* be_o  = (const float*)d_in[9];
  const float* Wu    = (const float*)d_in[10];
  const float* bu    = (const float*)d_in[11];
  const float* Wr    = (const float*)d_in[12];
  const float* br    = (const float*)d_in[13];
  const float* Wn    = (const float*)d_in[14];
  const float* bn    = (const float*)d_in[15];
  float* out = (float*)d_out;

  // ---- workspace (~70 MB)
  char* ws = (char*)d_ws;
  unsigned short* Wtp   = (unsigned short*)ws; ws += 1572864;   // 1024x768 bf16
  unsigned short* pwb   = (unsigned short*)ws; ws += 1572864;   // 1024x768 bf16
  unsigned short* attnb = (unsigned short*)ws; ws += 4194304;   // 16x64x2048 bf16
  float*          rowsum= (float*)ws;          ws += 4096;      // 1024 f32
  float*          parts = (float*)ws;          ws += 6291456;   // 2x 1024x768 f32
  float*          routed= (float*)ws;          ws += 4194304;   // 1024x1024 f32
  unsigned short* conc  = (unsigned short*)ws; ws += 4194304;   // 1024x2048 bf16
  unsigned short* candA = (unsigned short*)ws; ws += 4194304;   // 1024x2048 bf16
  float*          ubuf  = (float*)ws;          ws += 4194304;   // 1024x1024 f32
  unsigned short* Wtur  = (unsigned short*)ws; ws += 8388608;   // 2048x2048 bf16
  unsigned short* Wtn   = (unsigned short*)ws; ws += 4194304;   // 1024x2048 bf16
  float*          gparts= (float*)ws;          ws += 16777216;  // 2x 1024x2048 f32
  float*          cparts= (float*)ws;          ws += 8388608;   // 2x 1024x1024 f32

  const dim3 blk(256);

  // 1. merged: pw GEMM (f32-direct) + 4 transposes + rowsum zero
  k_prep_pw<<<dim3(7104), blk, 0, stream>>>(prev, Wp, Wu, Wr, Wn,
                                            Wtur, Wtn, Wtp, pwb, rowsum);
  // 2. attnb = exp(pw @ tokens^T / 32) + fused rowsum atomics, 512 blocks
  k_scores<<<dim3(1, 32, 16), blk, 0, stream>>>(
      pwb, 49152L, 768, toks, 768, 0.03125f,
      attnb, 2048, 131072L, rowsum);
  // 3. rw partials = w @ tokens(f32), K-split x2, 384 blocks
  k_routed_mfma<<<dim3(2, 12, 16), blk, 0, stream>>>(attnb, toks, parts);
  // 4. merged: proj2 (256 blocks) + prev-LN (1024 blocks)
  k_proj2_ln<<<dim3(1280), blk, 0, stream>>>(
      parts, 768, Wtp, 768, 768, bp, rowsum, routed, 1024,
      prev, g_st, be_st, conc);
  // 5. routed LN -> conc/candA second halves
  k_ln_routed<<<dim3(1024), blk, 0, stream>>>(routed, g_in, be_in, conc, candA);
  // 6. u|r gates GEMM, K-split x2 (f32 partials), 1024 blocks
  k_gemm64<<<dim3(16, 32, 2), blk, 0, stream>>>(
      conc, 2048, Wtur, 2048, 1024, 2097152L, gparts, 2048);
  // 7. gates epilogue: sigmoid + r*ps_n, 2048 blocks
  k_gate_epi<<<dim3(2048), blk, 0, stream>>>(gparts, bu, br, conc, ubuf, candA);
  // 8. cand GEMM, K-split x2 (f32 partials), 512 blocks
  k_gemm64<<<dim3(16, 16, 2), blk, 0, stream>>>(
      candA, 2048, Wtn, 2048, 1024, 1048576L, cparts, 1024);
  // 9. fused cand-epilogue + final LN -> output
  k_ln_out<<<dim3(1024), blk, 0, stream>>>(cparts, ubuf, prev, bn, g_o, be_o, out);
}